// Round 11
// baseline (414.472 us; speedup 1.0000x reference)
//
#include <hip/hip_runtime.h>

#define N_ 16384
#define E_ 131072
#define G_ 32
#define EPSF 1e-5f

typedef unsigned short bf16u;
typedef __attribute__((ext_vector_type(8))) short s8v;   // 8 bf16 (4 VGPRs)
typedef __attribute__((ext_vector_type(4))) float f4v;   // 4 fp32 acc

__device__ __forceinline__ bf16u f2bf(float v) {
    union { float f; unsigned u; } x; x.f = v;
    unsigned r = x.u + 0x7FFF + ((x.u >> 16) & 1);   // RNE
    return (bf16u)(r >> 16);
}
__device__ __forceinline__ float bf2f(bf16u u) {
    union { unsigned u; float f; } x; x.u = (unsigned)u << 16;
    return x.f;
}

// ---------------- workspace layout (bytes) ----------------
static const size_t OFF_INDEG = 0;          // int[N]        } single
static const size_t OFF_ROWS  = 65536;      // int[N+1]      } memset
static const size_t OFF_CURSOR= 131584;     // int[N]        } covers
static const size_t OFF_CSR   = 197120;     // int[E]        } 0..OFF_XA1
static const size_t OFF_DIS   = 721408;     // float[N]
static const size_t OFF_ES    = 786944;     // float[4N]
static const size_t OFF_ED    = 1049088;    // float[4N]
static const size_t OFF_BNS   = 1311232;    // float[4][512]
static const size_t OFF_BNQ   = 1319424;    // float[4][512]
static const size_t OFF_GB    = 1327616;    // int[33]
static const size_t OFF_POOL  = 1327872;    // float[32*1024]
static const size_t OFF_XA1   = 1458944;    // (unused, kept as memset end marker)
static const size_t OFF_H1    = 1786624;    // float[64N]   4 MB
static const size_t OFF_AB    = 5980928;    // bf16[128N]   4 MB ([agg|h1] concat)
static const size_t OFF_H2P   = 10175232;   // bf16[128N]   4 MB (pre-BN)
static const size_t OFF_H2B   = 14369536;   // bf16[128N]   4 MB (post-BN)
static const size_t OFF_H3B   = 18563840;   // bf16[256N]   8 MB
static const size_t OFF_HGAT  = 35328768;   // bf16[1024N]  32 MB (channel-major [node][c*4+h])
static const size_t OFF_XA4B  = OFF_HGAT;   // bf16[256N] 8 MB (hgat dead by then)
static const size_t OFF_WT1   = 68883200;   // bf16[1024*128] (row-PERMUTED gat_w^T)
static const size_t OFF_WT2   = 69145344;   // bf16[512*256]
static const size_t OFF_WT3   = 69407488;   // bf16[128*128]
static const size_t OFF_H4B   = 69440256;   // bf16[512N] 16 MB
static const size_t OFF_EM    = 86217472;   // float[4N] per-node logit max
// total ≈ 86.5 MB

// ---------------- graph structure ----------------
__global__ void k_indeg(const int* __restrict__ dst, int* __restrict__ indeg) {
    int e = blockIdx.x * 256 + threadIdx.x;
    if (e < E_) atomicAdd(&indeg[dst[e]], 1);
}

// scan + fused dis + cursor copy (kills the D2D memcpy node)
__global__ __launch_bounds__(1024) void k_scan(const int* __restrict__ indeg,
                                               int* __restrict__ rows,
                                               int* __restrict__ cursor,
                                               float* __restrict__ dis) {
    __shared__ int part[1024];
    int t = threadIdx.x;
    int base = t * 16;
    int local[16];
    int s = 0;
#pragma unroll
    for (int i = 0; i < 16; ++i) {
        local[i] = indeg[base + i]; s += local[i];
        dis[base + i] = rsqrtf((float)local[i] + 1.0f);
    }
    part[t] = s;
    __syncthreads();
    for (int off = 1; off < 1024; off <<= 1) {
        int v = (t >= off) ? part[t - off] : 0;
        __syncthreads();
        part[t] += v;
        __syncthreads();
    }
    int run = (t == 0) ? 0 : part[t - 1];
#pragma unroll
    for (int i = 0; i < 16; ++i) {
        rows[base + i] = run; cursor[base + i] = run; run += local[i];
    }
    if (t == 1023) rows[N_] = run;
}

__global__ void k_fill(const int* __restrict__ src, const int* __restrict__ dst,
                       int* __restrict__ cursor, int* __restrict__ csr) {
    int e = blockIdx.x * 256 + threadIdx.x;
    if (e < E_) {
        int p = atomicAdd(&cursor[dst[e]], 1);
        csr[p] = src[e];
    }
}

// ---------------- fused weight transpose+convert + gbounds (1 dispatch) ----------------
// wT1 rows are PERMUTED (m' = c*4+h -> source col h*256+c) so the GAT GEMM
// natively emits channel-major hgat with coalesced stores (round-9 lesson:
// permute the weight, never scatter-store the 32 MB output).
__global__ void k_wconv_all(const float* __restrict__ gat_w,
                            const float* __restrict__ gcn4_w,
                            const float* __restrict__ wl, const float* __restrict__ wr,
                            const int* __restrict__ batch,
                            bf16u* __restrict__ wT1, bf16u* __restrict__ wT2,
                            bf16u* __restrict__ wT3, int* __restrict__ gb) {
    int idx = blockIdx.x * 256 + threadIdx.x;
    if (idx < 131072) {          // gat_w [128][1024] -> wT1[m'=c*4+h][128]
        int m = idx >> 7, k = idx & 127;
        int col = (m & 3) * 256 + (m >> 2);     // h = m&3, c = m>>2
        wT1[idx] = f2bf(gat_w[(size_t)k * 1024 + col]);
    } else if (idx < 262144) {   // gcn4_w [256][512] -> wT2[512][256]
        int j = idx - 131072;
        int m = j >> 8, k = j & 255;
        wT2[j] = f2bf(gcn4_w[(size_t)k * 512 + m]);
    } else if (idx < 278528) {   // [wl;wr] -> wT3[128][128]
        int j = idx - 262144;
        int m = j >> 7, k = j & 127;
        float v = (k < 64) ? wl[k*128 + m] : wr[(k-64)*128 + m];
        wT3[j] = f2bf(v);
    } else {                     // graph-batch bounds (was k_gbounds)
        int g = idx - 278528;
        if (g > G_) return;
        if (g == G_) { gb[G_] = N_; return; }
        int lo = 0, hi = N_;
        while (lo < hi) { int mid = (lo + hi) >> 1; if (batch[mid] < g) lo = mid + 1; else hi = mid; }
        gb[g] = lo;
    }
}

// ---------------- layer 1: fused GCN aggregate(5) + matmul(5->64), wave-per-node ----------------
// Butterfly reduce leaves the 5 aggregates in ALL lanes; lane l then computes
// h1[i][l] directly (w is 1.25 KB, L1-resident broadcast). Was 2 kernels + xa1.
__global__ __launch_bounds__(256) void k_gcn1(const float* __restrict__ x,
                                              const float* __restrict__ dis,
                                              const int* __restrict__ rows,
                                              const int* __restrict__ csr,
                                              const float* __restrict__ w,
                                              const float* __restrict__ b,
                                              float* __restrict__ h1) {
    int wave = threadIdx.x >> 6, lane = threadIdx.x & 63;
    int i = blockIdx.x * 4 + wave;
    float a0=0,a1=0,a2=0,a3=0,a4=0;
    int e0 = rows[i], e1 = rows[i+1];
    for (int e = e0 + lane; e < e1; e += 64) {
        int s = csr[e];
        float wt = dis[s];
        a0 += x[s*5+0]*wt; a1 += x[s*5+1]*wt; a2 += x[s*5+2]*wt;
        a3 += x[s*5+3]*wt; a4 += x[s*5+4]*wt;
    }
#pragma unroll
    for (int off = 32; off > 0; off >>= 1) {
        a0 += __shfl_xor(a0, off, 64); a1 += __shfl_xor(a1, off, 64);
        a2 += __shfl_xor(a2, off, 64); a3 += __shfl_xor(a3, off, 64);
        a4 += __shfl_xor(a4, off, 64);
    }
    float di = dis[i];
    float xa0 = di*(a0 + di*x[i*5+0]);
    float xa1v = di*(a1 + di*x[i*5+1]);
    float xa2 = di*(a2 + di*x[i*5+2]);
    float xa3 = di*(a3 + di*x[i*5+3]);
    float xa4 = di*(a4 + di*x[i*5+4]);
    float hv = b[lane] + xa0*w[lane] + xa1v*w[64+lane] + xa2*w[128+lane]
             + xa3*w[192+lane] + xa4*w[256+lane];
    h1[(size_t)i*64 + lane] = hv;
}

// ---------------- batchnorm stats (fp32, C=64) ----------------
__global__ void k_bn_stats(const float* __restrict__ x, float* __restrict__ sum,
                           float* __restrict__ sumsq, int C, int rowsPerBlock) {
    int t = threadIdx.x;
    size_t base = (size_t)blockIdx.x * rowsPerBlock * C;
    size_t end  = base + (size_t)rowsPerBlock * C;
    float s0=0,q0=0;
    for (size_t f = base + t; f < end; f += 256) {
        float v = x[f]; s0 += v; q0 += v*v;
    }
    __shared__ float ls[256], lq[256];
    ls[t]=s0; lq[t]=q0;
    __syncthreads();
    if (t < C) {
        for (int j = t + C; j < 256; j += C) { s0 += ls[j]; q0 += lq[j]; }
        atomicAdd(&sum[t], s0); atomicAdd(&sumsq[t], q0);
    }
}

// ---------------- batchnorm stats (bf16, C=128/256/512) ----------------
__global__ void k_bn_stats_b(const bf16u* __restrict__ x, float* __restrict__ sum,
                             float* __restrict__ sumsq, int C, int rowsPerBlock) {
    int t = threadIdx.x;
    size_t base = (size_t)blockIdx.x * rowsPerBlock * C;
    size_t end  = base + (size_t)rowsPerBlock * C;
    if (C == 512) {
        float s0=0,q0=0,s1=0,q1=0;
        for (size_t f = base + t; f < end; f += 512) {
            float v = bf2f(x[f]);     s0 += v; q0 += v*v;
            float w = bf2f(x[f+256]); s1 += w; q1 += w*w;
        }
        atomicAdd(&sum[t], s0);      atomicAdd(&sumsq[t], q0);
        atomicAdd(&sum[t+256], s1);  atomicAdd(&sumsq[t+256], q1);
    } else {  // C <= 256
        float s0=0,q0=0;
        for (size_t f = base + t; f < end; f += 256) {
            float v = bf2f(x[f]); s0 += v; q0 += v*v;
        }
        atomicAdd(&sum[t & (C-1)], s0); atomicAdd(&sumsq[t & (C-1)], q0);
    }
}

// ---------------- BN1 apply: fp32 h1 -> bf16 mirror in ab[:,64:128] only ----------------
__global__ void k_bn_apply1(const float* __restrict__ h, const float* __restrict__ sum,
                            const float* __restrict__ sumsq, const float* __restrict__ g,
                            const float* __restrict__ b, bf16u* __restrict__ ab) {
    int idx = blockIdx.x * 256 + threadIdx.x;   // N*64
    int c = idx & 63, row = idx >> 6;
    const float invN = 1.0f / (float)N_;
    float mu  = sum[c] * invN;
    float var = sumsq[c] * invN - mu * mu;
    float v = (h[idx] - mu) * rsqrtf(var + EPSF) * g[c] + b[c];
    v = v > 0.f ? v : 0.f;
    ab[(size_t)row * 128 + 64 + c] = f2bf(v);
}

// ---------------- BN2 apply: bf16 pre -> bf16 post ----------------
__global__ void k_bn_apply2b(const bf16u* __restrict__ hp, const float* __restrict__ sum,
                             const float* __restrict__ sumsq, const float* __restrict__ g,
                             const float* __restrict__ b, bf16u* __restrict__ hb) {
    int idx = blockIdx.x * 256 + threadIdx.x;   // N*128
    int c = idx & 127;
    const float invN = 1.0f / (float)N_;
    float mu  = sum[c] * invN;
    float var = sumsq[c] * invN - mu * mu;
    float v = (bf2f(hp[idx]) - mu) * rsqrtf(var + EPSF) * g[c] + b[c];
    hb[idx] = f2bf(v > 0.f ? v : 0.f);
}

// ---------------- SAGE aggregate (mean) from bf16 mirror -> ab[:,0:64] ----------------
__global__ void k_sage_agg(const int* __restrict__ rows, const int* __restrict__ csr,
                           bf16u* __restrict__ ab) {
    int i = blockIdx.x * 4 + (threadIdx.x >> 6);
    int c = threadIdx.x & 63;
    int e0 = rows[i], e1 = rows[i+1];
    float s = 0.f;
    for (int e = e0; e < e1; ++e) s += bf2f(ab[(size_t)csr[e]*128 + 64 + c]);
    ab[(size_t)i*128 + c] = f2bf(s / fmaxf((float)(e1 - e0), 1.0f));
}

// ---------------- bf16 MFMA GEMM: C[n,m] = A[n,k]*BT[m,k]^T (+bias) ----------------
// 128x128 tile, BK=32, 4 waves x (4x4) mfma_f32_16x16x32_bf16 (layouts m89/m91/m120).
// Round-7 lesson: no reduction epilogues (full 64-VGPR acc stays live -> slow).
// Round-9 lesson: no permuted scatter-stores — permute the weight instead.
__global__ __launch_bounds__(256) void k_gemm_mfma(const bf16u* __restrict__ A,
                                                   const bf16u* __restrict__ BT,
                                                   const float* __restrict__ bias,
                                                   float* __restrict__ C,
                                                   int K, int M, int obf) {
    __shared__ bf16u As[128][40];
    __shared__ bf16u Bs[128][40];
    int tid = threadIdx.x;
    int wave = tid >> 6, lane = tid & 63;
    int wr = (wave >> 1) * 64, wc = (wave & 1) * 64;
    int row0 = blockIdx.y * 128, col0 = blockIdx.x * 128;
    f4v acc[4][4];
#pragma unroll
    for (int i = 0; i < 4; ++i)
#pragma unroll
        for (int j = 0; j < 4; ++j) acc[i][j] = (f4v)0.0f;

    int sr = tid >> 1;             // 0..127
    int sh = (tid & 1) * 16;       // k-half within BK
    int lr = lane & 15, lq = lane >> 4;

    for (int k0 = 0; k0 < K; k0 += 32) {
        const bf16u* ap = A + (size_t)(row0 + sr) * K + k0 + sh;
        *(uint4*)&As[sr][sh]     = *(const uint4*)ap;
        *(uint4*)&As[sr][sh + 8] = *(const uint4*)(ap + 8);
        const bf16u* bp = BT + (size_t)(col0 + sr) * K + k0 + sh;
        *(uint4*)&Bs[sr][sh]     = *(const uint4*)bp;
        *(uint4*)&Bs[sr][sh + 8] = *(const uint4*)(bp + 8);
        __syncthreads();
        s8v af[4], bfr[4];
#pragma unroll
        for (int i = 0; i < 4; ++i)
            af[i] = *(const s8v*)&As[wr + i*16 + lr][lq*8];
#pragma unroll
        for (int j = 0; j < 4; ++j)
            bfr[j] = *(const s8v*)&Bs[wc + j*16 + lr][lq*8];
#pragma unroll
        for (int i = 0; i < 4; ++i)
#pragma unroll
            for (int j = 0; j < 4; ++j)
                acc[i][j] = __builtin_amdgcn_mfma_f32_16x16x32_bf16(af[i], bfr[j], acc[i][j], 0, 0, 0);
        __syncthreads();
    }

    if (obf) {
        bf16u* Cb = (bf16u*)C;
#pragma unroll
        for (int i = 0; i < 4; ++i)
#pragma unroll
            for (int j = 0; j < 4; ++j) {
                int col = col0 + wc + j*16 + lr;
                float bv = bias ? bias[col] : 0.f;
#pragma unroll
                for (int r = 0; r < 4; ++r) {
                    int row = row0 + wr + i*16 + lq*4 + r;
                    Cb[(size_t)row * M + col] = f2bf(acc[i][j][r] + bv);
                }
            }
    } else {
#pragma unroll
        for (int i = 0; i < 4; ++i)
#pragma unroll
            for (int j = 0; j < 4; ++j) {
                int col = col0 + wc + j*16 + lr;
                float bv = bias ? bias[col] : 0.f;
#pragma unroll
                for (int r = 0; r < 4; ++r) {
                    int row = row0 + wr + i*16 + lq*4 + r;
                    C[(size_t)row * M + col] = acc[i][j][r] + bv;
                }
            }
    }
}

// ---------------- GAT attention coefficients: wave-per-node, channel-major hgat ----------------
__global__ __launch_bounds__(256) void k_gat_attn(const bf16u* __restrict__ hg,
                                                  const float* __restrict__ asrc,
                                                  const float* __restrict__ adst,
                                                  float* __restrict__ es,
                                                  float* __restrict__ ed) {
    int wave = threadIdx.x >> 6, lane = threadIdx.x & 63;
    int i = blockIdx.x * 4 + wave;
    const bf16u* hp = hg + (size_t)i*1024 + lane*16;   // 16 contig bf16: 4 channels x 4 heads
    float xc[4][4];    // [k][h], channel c = lane*4+k
#pragma unroll
    for (int k = 0; k < 4; ++k) {
        ushort4 u = *(const ushort4*)(hp + k*4);
        xc[k][0] = bf2f(u.x); xc[k][1] = bf2f(u.y);
        xc[k][2] = bf2f(u.z); xc[k][3] = bf2f(u.w);
    }
    float vs[4], vd[4];
#pragma unroll
    for (int h = 0; h < 4; ++h) {
        float4 a = *(const float4*)&asrc[h*256 + lane*4];
        float4 d = *(const float4*)&adst[h*256 + lane*4];
        vs[h] = xc[0][h]*a.x + xc[1][h]*a.y + xc[2][h]*a.z + xc[3][h]*a.w;
        vd[h] = xc[0][h]*d.x + xc[1][h]*d.y + xc[2][h]*d.z + xc[3][h]*d.w;
    }
#pragma unroll
    for (int off = 32; off > 0; off >>= 1) {
#pragma unroll
        for (int h = 0; h < 4; ++h) {
            vs[h] += __shfl_xor(vs[h], off, 64);
            vd[h] += __shfl_xor(vd[h], off, 64);
        }
    }
    if (lane == 0) {
        *(float4*)&es[i*4] = make_float4(vs[0], vs[1], vs[2], vs[3]);
        *(float4*)&ed[i*4] = make_float4(vd[0], vd[1], vd[2], vd[3]);
    }
}

// ---------------- per-node exact logit max (incl self-loop), wave-per-node ----------------
__global__ __launch_bounds__(256) void k_gat_max(const float* __restrict__ es,
                                                 const float* __restrict__ ed,
                                                 const int* __restrict__ rows,
                                                 const int* __restrict__ csr,
                                                 float* __restrict__ em) {
    int wave = threadIdx.x >> 6, lane = threadIdx.x & 63;
    int i = blockIdx.x * 4 + wave;
    float4 edv = *(const float4*)&ed[i*4];
    float4 sv = *(const float4*)&es[i*4];
    float e, m0, m1, m2, m3;
    e = sv.x + edv.x; m0 = e >= 0.f ? e : 0.2f*e;
    e = sv.y + edv.y; m1 = e >= 0.f ? e : 0.2f*e;
    e = sv.z + edv.z; m2 = e >= 0.f ? e : 0.2f*e;
    e = sv.w + edv.w; m3 = e >= 0.f ? e : 0.2f*e;
    int e0 = rows[i], e1 = rows[i+1];
    for (int ee = e0 + lane; ee < e1; ee += 64) {
        int s = csr[ee];
        float4 s2 = *(const float4*)&es[s*4];
        e = s2.x + edv.x; m0 = fmaxf(m0, e >= 0.f ? e : 0.2f*e);
        e = s2.y + edv.y; m1 = fmaxf(m1, e >= 0.f ? e : 0.2f*e);
        e = s2.z + edv.z; m2 = fmaxf(m2, e >= 0.f ? e : 0.2f*e);
        e = s2.w + edv.w; m3 = fmaxf(m3, e >= 0.f ? e : 0.2f*e);
    }
#pragma unroll
    for (int off = 32; off > 0; off >>= 1) {
        m0 = fmaxf(m0, __shfl_xor(m0, off, 64));
        m1 = fmaxf(m1, __shfl_xor(m1, off, 64));
        m2 = fmaxf(m2, __shfl_xor(m2, off, 64));
        m3 = fmaxf(m3, __shfl_xor(m3, off, 64));
    }
    if (lane == 0) *(float4*)&em[i*4] = make_float4(m0, m1, m2, m3);
}

// ---------------- GAT aggregate: single-pass softmax, ushort4 gather, z in LDS ----------------
// z sums are identical across all 256 threads -> computed once via LDS atomics
// in the staging loop (saves 4 VALU/edge/thread in the hot loop). LDS +16 B,
// VGPR -4: occupancy envelope of the proven 45us kernel preserved.
#define GCH 256
__global__ __launch_bounds__(256) void k_gat_agg(const bf16u* __restrict__ hg,
                                                 const float* __restrict__ es,
                                                 const float* __restrict__ ed,
                                                 const float* __restrict__ em,
                                                 const int* __restrict__ rows,
                                                 const int* __restrict__ csr,
                                                 const float* __restrict__ gbias,
                                                 bf16u* __restrict__ out) {
    __shared__ float4 se4[GCH];
    __shared__ int ssrc[GCH];
    __shared__ float sz[4];
    int i = blockIdx.x, t = threadIdx.x;
    float4 edv = *(const float4*)&ed[i*4];
    float4 emv = *(const float4*)&em[i*4];
    float a0, a1, a2, a3;
    {
        float4 sv = *(const float4*)&es[i*4];
        float e, ez0, ez1, ez2, ez3;
        e = sv.x + edv.x; e = e >= 0.f ? e : 0.2f*e; ez0 = __expf(e - emv.x);
        e = sv.y + edv.y; e = e >= 0.f ? e : 0.2f*e; ez1 = __expf(e - emv.y);
        e = sv.z + edv.z; e = e >= 0.f ? e : 0.2f*e; ez2 = __expf(e - emv.z);
        e = sv.w + edv.w; e = e >= 0.f ? e : 0.2f*e; ez3 = __expf(e - emv.w);
        ushort4 u = *(const ushort4*)(hg + (size_t)i*1024 + t*4);
        a0 = ez0 * bf2f(u.x); a1 = ez1 * bf2f(u.y);
        a2 = ez2 * bf2f(u.z); a3 = ez3 * bf2f(u.w);
        if (t == 0) { sz[0] = ez0; sz[1] = ez1; sz[2] = ez2; sz[3] = ez3; }
    }
    __syncthreads();   // sz init visible before staging atomics
    int e0 = rows[i], e1 = rows[i+1];
    for (int c0 = e0; c0 < e1; c0 += GCH) {
        int cn = min(GCH, e1 - c0);
        for (int j = t; j < cn; j += 256) {
            int s = csr[c0 + j];
            ssrc[j] = s;
            float4 sv = *(const float4*)&es[s*4];
            float4 v; float e;
            e = sv.x + edv.x; e = e >= 0.f ? e : 0.2f*e; v.x = __expf(e - emv.x);
            e = sv.y + edv.y; e = e >= 0.f ? e : 0.2f*e; v.y = __expf(e - emv.y);
            e = sv.z + edv.z; e = e >= 0.f ? e : 0.2f*e; v.z = __expf(e - emv.z);
            e = sv.w + edv.w; e = e >= 0.f ? e : 0.2f*e; v.w = __expf(e - emv.w);
            se4[j] = v;
            atomicAdd(&sz[0], v.x); atomicAdd(&sz[1], v.y);
            atomicAdd(&sz[2], v.z); atomicAdd(&sz[3], v.w);
        }
        __syncthreads();
        for (int j = 0; j < cn; ++j) {
            float4 ex = se4[j];
            ushort4 u = *(const ushort4*)(hg + (size_t)ssrc[j]*1024 + t*4);
            a0 += ex.x * bf2f(u.x);
            a1 += ex.y * bf2f(u.y);
            a2 += ex.z * bf2f(u.z);
            a3 += ex.w * bf2f(u.w);
        }
        __syncthreads();
    }
    float o = 0.25f * (a0/sz[0] + a1/sz[1] + a2/sz[2] + a3/sz[3]);
    out[(size_t)i*256 + t] = f2bf(o + gbias[t]);
}

// ---------------- layer 4: fused BN3+ReLU + GCN aggregate (wave-per-node, ushort4) ----------------
__global__ __launch_bounds__(256) void k_gcn4_agg(const bf16u* __restrict__ h3b,
                                                  const float* __restrict__ dis,
                                                  const int* __restrict__ rows,
                                                  const int* __restrict__ csr,
                                                  const float* __restrict__ sum,
                                                  const float* __restrict__ sumsq,
                                                  const float* __restrict__ g,
                                                  const float* __restrict__ b,
                                                  bf16u* __restrict__ xab) {
    int wave = threadIdx.x >> 6, q = threadIdx.x & 63;
    int i = blockIdx.x * 4 + wave;
    int c = q * 4;
    const float invN = 1.0f / (float)N_;
    float4 sm = *(const float4*)&sum[c];
    float4 sq = *(const float4*)&sumsq[c];
    float4 gg = *(const float4*)&g[c];
    float4 bb = *(const float4*)&b[c];
    float mu, sc0, sc1, sc2, sc3, sh0, sh1, sh2, sh3;
    mu = sm.x*invN; sc0 = rsqrtf(sq.x*invN - mu*mu + EPSF)*gg.x; sh0 = bb.x - mu*sc0;
    mu = sm.y*invN; sc1 = rsqrtf(sq.y*invN - mu*mu + EPSF)*gg.y; sh1 = bb.y - mu*sc1;
    mu = sm.z*invN; sc2 = rsqrtf(sq.z*invN - mu*mu + EPSF)*gg.z; sh2 = bb.z - mu*sc2;
    mu = sm.w*invN; sc3 = rsqrtf(sq.w*invN - mu*mu + EPSF)*gg.w; sh3 = bb.w - mu*sc3;
    float di = dis[i];
    float a0, a1, a2, a3;
    {
        ushort4 u = *(const ushort4*)(h3b + (size_t)i*256 + c);
        float v, dd = di * di;
        v = fmaf(bf2f(u.x), sc0, sh0); v = v > 0.f ? v : 0.f; a0 = v * dd;
        v = fmaf(bf2f(u.y), sc1, sh1); v = v > 0.f ? v : 0.f; a1 = v * dd;
        v = fmaf(bf2f(u.z), sc2, sh2); v = v > 0.f ? v : 0.f; a2 = v * dd;
        v = fmaf(bf2f(u.w), sc3, sh3); v = v > 0.f ? v : 0.f; a3 = v * dd;
    }
    int e0 = rows[i], e1 = rows[i+1];
    for (int e = e0; e < e1; ++e) {
        int s = csr[e];
        float w = dis[s] * di;
        ushort4 u = *(const ushort4*)(h3b + (size_t)s*256 + c);
        float v;
        v = fmaf(bf2f(u.x), sc0, sh0); v = v > 0.f ? v : 0.f; a0 += v * w;
        v = fmaf(bf2f(u.y), sc1, sh1); v = v > 0.f ? v : 0.f; a1 += v * w;
        v = fmaf(bf2f(u.z), sc2, sh2); v = v > 0.f ? v : 0.f; a2 += v * w;
        v = fmaf(bf2f(u.w), sc3, sh3); v = v > 0.f ? v : 0.f; a3 += v * w;
    }
    ushort4 o;
    o.x = f2bf(a0); o.y = f2bf(a1); o.z = f2bf(a2); o.w = f2bf(a3);
    *(ushort4*)(xab + (size_t)i*256 + c) = o;
}

// ---------------- pooling with fused BN4+ReLU ----------------
__global__ void k_pool(const bf16u* __restrict__ h4b, const int* __restrict__ gb,
                       const float* __restrict__ sum, const float* __restrict__ sumsq,
                       const float* __restrict__ g, const float* __restrict__ b,
                       float* __restrict__ pooled) {
    int gi = blockIdx.y;
    int t = threadIdx.x;
    const float invN = 1.0f / (float)N_;
    float mu0 = sum[t] * invN;
    float sc0 = rsqrtf(sumsq[t] * invN - mu0*mu0 + EPSF) * g[t];
    float sh0 = b[t] - mu0 * sc0;
    float mu1 = sum[t+256] * invN;
    float sc1 = rsqrtf(sumsq[t+256] * invN - mu1*mu1 + EPSF) * g[t+256];
    float sh1 = b[t+256] - mu1 * sc1;
    int r0g = gb[gi], r1g = gb[gi+1];
    int n = r1g - r0g;
    if (n <= 0) return;
    int per = (n + 15) >> 4;
    int r0 = r0g + blockIdx.x * per;
    int r1 = min(r0 + per, r1g);
    if (r0 >= r1) return;
    float s0=0.f, s1=0.f, m0=0.f, m1=0.f;   // post-ReLU >= 0: max init 0 valid
    for (int r = r0; r < r1; ++r) {
        float v = fmaf(bf2f(h4b[(size_t)r*512 + t]), sc0, sh0);
        v = v > 0.f ? v : 0.f;
        s0 += v; m0 = fmaxf(m0, v);
        float w = fmaf(bf2f(h4b[(size_t)r*512 + 256 + t]), sc1, sh1);
        w = w > 0.f ? w : 0.f;
        s1 += w; m1 = fmaxf(m1, w);
    }
    atomicAdd(&pooled[gi*1024 + t], s0);
    atomicAdd(&pooled[gi*1024 + 256 + t], s1);
    atomicMax((int*)&pooled[gi*1024 + 512 + t],  __float_as_int(m0));
    atomicMax((int*)&pooled[gi*1024 + 768 + t],  __float_as_int(m1));
}

// ---------------- FC (K-split, float4, atomic reduce; mean-scale folded in) ----------------
#define FCKZ 16
#define FCKC (1024 / FCKZ)   // 64

__global__ void k_fc_init(const float* __restrict__ b, float* __restrict__ out) {
    int i = blockIdx.x * 256 + threadIdx.x;   // 32*1024
    out[i] = b[i & 1023];
}

__global__ __launch_bounds__(256) void k_fc2(const float* __restrict__ pooled,
                                             const float* __restrict__ w,
                                             const int* __restrict__ gb,
                                             float* __restrict__ out) {
    __shared__ float pr[FCKC];
    int g = blockIdx.x;
    int z = blockIdx.y;
    int t = threadIdx.x;
    int k0 = z * FCKC;
    if (t < FCKC) {
        float scale = (z < 8) ? 1.0f / fmaxf((float)(gb[g+1] - gb[g]), 1.0f) : 1.0f;
        pr[t] = pooled[g * 1024 + k0 + t] * scale;   // mean part needs 1/cnt (pool_fin folded)
    }
    __syncthreads();
    int m0 = t * 4;
    float ax = 0.f, ay = 0.f, az = 0.f, aw = 0.f;
#pragma unroll 8
    for (int k = 0; k < FCKC; ++k) {
        const float4 wv = *(const float4*)&w[(size_t)(k0 + k) * 1024 + m0];
        float p = pr[k];
        ax += p * wv.x; ay += p * wv.y; az += p * wv.z; aw += p * wv.w;
    }
    atomicAdd(&out[g * 1024 + m0 + 0], ax);
    atomicAdd(&out[g * 1024 + m0 + 1], ay);
    atomicAdd(&out[g * 1024 + m0 + 2], az);
    atomicAdd(&out[g * 1024 + m0 + 3], aw);
}

// ---------------- host ----------------
extern "C" void kernel_launch(void* const* d_in, const int* in_sizes, int n_in,
                              void* d_out, int out_size, void* d_ws, size_t ws_size,
                              hipStream_t stream) {
    (void)in_sizes; (void)n_in; (void)out_size; (void)ws_size;
    const float* x       = (const float*)d_in[0];
    const int*   ei      = (const int*)d_in[1];
    const int*   batch   = (const int*)d_in[2];
    const float* gcn1_w  = (const float*)d_in[3];
    const float* gcn1_b  = (const float*)d_in[4];
    const float* sage_wl = (const float*)d_in[5];
    const float* sage_wr = (const float*)d_in[6];
    const float* sage_b  = (const float*)d_in[7];
    const float* gat_w   = (const float*)d_in[8];
    const float* gat_as  = (const float*)d_in[9];
    const float* gat_ad  = (const float*)d_in[10];
    const float* gat_b   = (const float*)d_in[11];
    const float* gcn4_w  = (const float*)d_in[12];
    const float* gcn4_b  = (const float*)d_in[13];
    const float* bn1_g   = (const float*)d_in[14];
    const float* bn1_b   = (const float*)d_in[15];
    const float* bn2_g   = (const float*)d_in[16];
    const float* bn2_b   = (const float*)d_in[17];
    const float* bn3_g   = (const float*)d_in[18];
    const float* bn3_b   = (const float*)d_in[19];
    const float* bn4_g   = (const float*)d_in[20];
    const float* bn4_b   = (const float*)d_in[21];
    const float* fc_w    = (const float*)d_in[22];
    const float* fc_b    = (const float*)d_in[23];
    float* out = (float*)d_out;

    char* w8 = (char*)d_ws;
    int*   indeg  = (int*)(w8 + OFF_INDEG);
    int*   rows   = (int*)(w8 + OFF_ROWS);
    int*   cursor = (int*)(w8 + OFF_CURSOR);
    int*   csr    = (int*)(w8 + OFF_CSR);
    float* dis    = (float*)(w8 + OFF_DIS);
    float* es     = (float*)(w8 + OFF_ES);
    float* ed     = (float*)(w8 + OFF_ED);
    float* bns    = (float*)(w8 + OFF_BNS);   // [4][512] per-layer slices
    float* bnq    = (float*)(w8 + OFF_BNQ);
    int*   gb     = (int*)(w8 + OFF_GB);
    float* pooled = (float*)(w8 + OFF_POOL);
    float* h1     = (float*)(w8 + OFF_H1);
    bf16u* ab     = (bf16u*)(w8 + OFF_AB);
    bf16u* h2p    = (bf16u*)(w8 + OFF_H2P);
    bf16u* h2b    = (bf16u*)(w8 + OFF_H2B);
    bf16u* h3b    = (bf16u*)(w8 + OFF_H3B);
    bf16u* hgat   = (bf16u*)(w8 + OFF_HGAT);
    bf16u* xa4b   = (bf16u*)(w8 + OFF_XA4B);
    bf16u* wT1    = (bf16u*)(w8 + OFF_WT1);
    bf16u* wT2    = (bf16u*)(w8 + OFF_WT2);
    bf16u* wT3    = (bf16u*)(w8 + OFF_WT3);
    bf16u* h4b    = (bf16u*)(w8 + OFF_H4B);
    float* em     = (float*)(w8 + OFF_EM);

    const int* srcE = ei;        // edge_index[0,:]
    const int* dstE = ei + E_;   // edge_index[1,:]

    const int BNB = 512;
    const int BNR = N_ / BNB;

    // ---- setup: ONE memset zeroes indeg..pooled (rows/cursor/csr/dis overwritten later) ----
    hipMemsetAsync(w8, 0, OFF_XA1, stream);
    k_indeg<<<E_/256, 256, 0, stream>>>(dstE, indeg);
    k_scan<<<1, 1024, 0, stream>>>(indeg, rows, cursor, dis);
    k_fill<<<E_/256, 256, 0, stream>>>(srcE, dstE, cursor, csr);
    k_wconv_all<<<1089, 256, 0, stream>>>(gat_w, gcn4_w, sage_wl, sage_wr, batch,
                                          wT1, wT2, wT3, gb);

    // ---- layer 1: fused GCN 5->64 (agg+matmul), BN, ReLU (bf16 mirror only) ----
    k_gcn1<<<N_/4, 256, 0, stream>>>(x, dis, rows, csr, gcn1_w, gcn1_b, h1);
    k_bn_stats<<<BNB, 256, 0, stream>>>(h1, bns, bnq, 64, BNR);
    k_bn_apply1<<<(N_*64)/256, 256, 0, stream>>>(h1, bns, bnq, bn1_g, bn1_b, ab);

    // ---- layer 2: SAGE 64->128 via single MFMA GEMM on [agg|h1], BN, ReLU ----
    k_sage_agg<<<N_/4, 256, 0, stream>>>(rows, csr, ab);
    {
        dim3 grid(1, N_/128);
        k_gemm_mfma<<<grid, 256, 0, stream>>>(ab, wT3, sage_b, (float*)h2p, 128, 128, 1);
    }
    k_bn_stats_b<<<BNB, 256, 0, stream>>>(h2p, bns + 512, bnq + 512, 128, BNR);
    k_bn_apply2b<<<(N_*128)/256, 256, 0, stream>>>(h2p, bns + 512, bnq + 512, bn2_g, bn2_b, h2b);

    // ---- layer 3: GAT GEMM (weight-permuted -> channel-major out), attention, max, aggregate ----
    {
        dim3 grid(1024/128, N_/128);
        k_gemm_mfma<<<grid, 256, 0, stream>>>(h2b, wT1, nullptr, (float*)hgat, 128, 1024, 1);
    }
    k_gat_attn<<<N_/4, 256, 0, stream>>>(hgat, gat_as, gat_ad, es, ed);
    k_gat_max<<<N_/4, 256, 0, stream>>>(es, ed, rows, csr, em);
    k_gat_agg<<<N_, 256, 0, stream>>>(hgat, es, ed, em, rows, csr, gat_b, h3b);
    k_bn_stats_b<<<BNB, 256, 0, stream>>>(h3b, bns + 1024, bnq + 1024, 256, BNR);

    // ---- layer 4: fused BN3+ReLU+aggregate, MFMA GEMM 256->512 (bf16 out) ----
    k_gcn4_agg<<<N_/4, 256, 0, stream>>>(h3b, dis, rows, csr, bns + 1024, bnq + 1024,
                                         bn3_g, bn3_b, xa4b);
    {
        dim3 grid(512/128, N_/128);
        k_gemm_mfma<<<grid, 256, 0, stream>>>(xa4b, wT2, gcn4_b, (float*)h4b, 256, 512, 1);
    }
    k_bn_stats_b<<<BNB, 256, 0, stream>>>(h4b, bns + 1536, bnq + 1536, 512, BNR);

    // ---- pooling with fused BN4+ReLU -> [32,1024] (mean scale folded into FC) ----
    {
        dim3 grid(16, G_);
        k_pool<<<grid, 256, 0, stream>>>(h4b, gb, bns + 1536, bnq + 1536, bn4_g, bn4_b, pooled);
    }

    // ---- FC 1024->1024 ----
    k_fc_init<<<(G_*1024)/256, 256, 0, stream>>>(fc_b, out);
    {
        dim3 grid(G_, FCKZ);
        k_fc2<<<grid, 256, 0, stream>>>(pooled, fc_w, gb, out);
    }
}

// Round 12
// 408.726 us; speedup vs baseline: 1.0141x; 1.0141x over previous
//
#include <hip/hip_runtime.h>

#define N_ 16384
#define E_ 131072
#define G_ 32
#define EPSF 1e-5f

typedef unsigned short bf16u;
typedef __attribute__((ext_vector_type(8))) short s8v;   // 8 bf16 (4 VGPRs)
typedef __attribute__((ext_vector_type(4))) float f4v;   // 4 fp32 acc

__device__ __forceinline__ bf16u f2bf(float v) {
    union { float f; unsigned u; } x; x.f = v;
    unsigned r = x.u + 0x7FFF + ((x.u >> 16) & 1);   // RNE
    return (bf16u)(r >> 16);
}
__device__ __forceinline__ float bf2f(bf16u u) {
    union { unsigned u; float f; } x; x.u = (unsigned)u << 16;
    return x.f;
}

// ---------------- workspace layout (bytes) ----------------
static const size_t OFF_INDEG = 0;          // int[N]        } single
static const size_t OFF_ROWS  = 65536;      // int[N+1]      } memset
static const size_t OFF_CURSOR= 131584;     // int[N]        } covers
static const size_t OFF_CSR   = 197120;     // int[E]        } 0..OFF_XA1
static const size_t OFF_DIS   = 721408;     // float[N]
static const size_t OFF_ES    = 786944;     // float[4N]
static const size_t OFF_ED    = 1049088;    // float[4N]
static const size_t OFF_BNS   = 1311232;    // float[4][512]
static const size_t OFF_BNQ   = 1319424;    // float[4][512]
static const size_t OFF_GB    = 1327616;    // int[33]
static const size_t OFF_POOL  = 1327872;    // float[32*1024]
static const size_t OFF_XA1   = 1458944;    // (memset end marker)
static const size_t OFF_H1    = 1786624;    // float[64N]   4 MB
static const size_t OFF_AB    = 5980928;    // bf16[128N]   4 MB ([agg|h1] concat)
static const size_t OFF_H2P   = 10175232;   // bf16[128N]   4 MB (pre-BN)
static const size_t OFF_H2B   = 14369536;   // bf16[128N]   4 MB (post-BN)
static const size_t OFF_H3B   = 18563840;   // bf16[256N]   8 MB
static const size_t OFF_HGAT  = 35328768;   // bf16[1024N]  32 MB (channel-major [node][c*4+h])
static const size_t OFF_XA4B  = OFF_HGAT;   // bf16[256N] 8 MB (hgat dead by then)
static const size_t OFF_WT1   = 68883200;   // bf16[1024*128] (row-PERMUTED gat_w^T)
static const size_t OFF_WT2   = 69145344;   // bf16[512*256]
static const size_t OFF_WT3   = 69407488;   // bf16[128*128]
static const size_t OFF_H4B   = 69440256;   // bf16[512N] 16 MB
static const size_t OFF_EM    = 86217472;   // float[4N] per-node logit max
// total ≈ 86.5 MB

// ---------------- graph structure ----------------
__global__ void k_indeg(const int* __restrict__ dst, int* __restrict__ indeg) {
    int e = blockIdx.x * 256 + threadIdx.x;
    if (e < E_) atomicAdd(&indeg[dst[e]], 1);
}

// scan + fused dis + cursor copy
__global__ __launch_bounds__(1024) void k_scan(const int* __restrict__ indeg,
                                               int* __restrict__ rows,
                                               int* __restrict__ cursor,
                                               float* __restrict__ dis) {
    __shared__ int part[1024];
    int t = threadIdx.x;
    int base = t * 16;
    int local[16];
    int s = 0;
#pragma unroll
    for (int i = 0; i < 16; ++i) {
        local[i] = indeg[base + i]; s += local[i];
        dis[base + i] = rsqrtf((float)local[i] + 1.0f);
    }
    part[t] = s;
    __syncthreads();
    for (int off = 1; off < 1024; off <<= 1) {
        int v = (t >= off) ? part[t - off] : 0;
        __syncthreads();
        part[t] += v;
        __syncthreads();
    }
    int run = (t == 0) ? 0 : part[t - 1];
#pragma unroll
    for (int i = 0; i < 16; ++i) {
        rows[base + i] = run; cursor[base + i] = run; run += local[i];
    }
    if (t == 1023) rows[N_] = run;
}

__global__ void k_fill(const int* __restrict__ src, const int* __restrict__ dst,
                       int* __restrict__ cursor, int* __restrict__ csr) {
    int e = blockIdx.x * 256 + threadIdx.x;
    if (e < E_) {
        int p = atomicAdd(&cursor[dst[e]], 1);
        csr[p] = src[e];
    }
}

// ---------------- fused weight transpose+convert + gbounds (1 dispatch) ----------------
// wT1 rows are PERMUTED (m' = c*4+h -> source col h*256+c): round-9 lesson —
// permute the weight, never scatter-store the 32 MB output.
__global__ void k_wconv_all(const float* __restrict__ gat_w,
                            const float* __restrict__ gcn4_w,
                            const float* __restrict__ wl, const float* __restrict__ wr,
                            const int* __restrict__ batch,
                            bf16u* __restrict__ wT1, bf16u* __restrict__ wT2,
                            bf16u* __restrict__ wT3, int* __restrict__ gb) {
    int idx = blockIdx.x * 256 + threadIdx.x;
    if (idx < 131072) {          // gat_w [128][1024] -> wT1[m'=c*4+h][128]
        int m = idx >> 7, k = idx & 127;
        int col = (m & 3) * 256 + (m >> 2);     // h = m&3, c = m>>2
        wT1[idx] = f2bf(gat_w[(size_t)k * 1024 + col]);
    } else if (idx < 262144) {   // gcn4_w [256][512] -> wT2[512][256]
        int j = idx - 131072;
        int m = j >> 8, k = j & 255;
        wT2[j] = f2bf(gcn4_w[(size_t)k * 512 + m]);
    } else if (idx < 278528) {   // [wl;wr] -> wT3[128][128]
        int j = idx - 262144;
        int m = j >> 7, k = j & 127;
        float v = (k < 64) ? wl[k*128 + m] : wr[(k-64)*128 + m];
        wT3[j] = f2bf(v);
    } else {                     // graph-batch bounds
        int g = idx - 278528;
        if (g > G_) return;
        if (g == G_) { gb[G_] = N_; return; }
        int lo = 0, hi = N_;
        while (lo < hi) { int mid = (lo + hi) >> 1; if (batch[mid] < g) lo = mid + 1; else hi = mid; }
        gb[g] = lo;
    }
}

// ---------------- layer 1: fused GCN aggregate(5) + matmul(5->64), wave-per-node ----------------
__global__ __launch_bounds__(256) void k_gcn1(const float* __restrict__ x,
                                              const float* __restrict__ dis,
                                              const int* __restrict__ rows,
                                              const int* __restrict__ csr,
                                              const float* __restrict__ w,
                                              const float* __restrict__ b,
                                              float* __restrict__ h1) {
    int wave = threadIdx.x >> 6, lane = threadIdx.x & 63;
    int i = blockIdx.x * 4 + wave;
    float a0=0,a1=0,a2=0,a3=0,a4=0;
    int e0 = rows[i], e1 = rows[i+1];
    for (int e = e0 + lane; e < e1; e += 64) {
        int s = csr[e];
        float wt = dis[s];
        a0 += x[s*5+0]*wt; a1 += x[s*5+1]*wt; a2 += x[s*5+2]*wt;
        a3 += x[s*5+3]*wt; a4 += x[s*5+4]*wt;
    }
#pragma unroll
    for (int off = 32; off > 0; off >>= 1) {
        a0 += __shfl_xor(a0, off, 64); a1 += __shfl_xor(a1, off, 64);
        a2 += __shfl_xor(a2, off, 64); a3 += __shfl_xor(a3, off, 64);
        a4 += __shfl_xor(a4, off, 64);
    }
    float di = dis[i];
    float xa0 = di*(a0 + di*x[i*5+0]);
    float xa1v = di*(a1 + di*x[i*5+1]);
    float xa2 = di*(a2 + di*x[i*5+2]);
    float xa3 = di*(a3 + di*x[i*5+3]);
    float xa4 = di*(a4 + di*x[i*5+4]);
    float hv = b[lane] + xa0*w[lane] + xa1v*w[64+lane] + xa2*w[128+lane]
             + xa3*w[192+lane] + xa4*w[256+lane];
    h1[(size_t)i*64 + lane] = hv;
}

// ---------------- batchnorm stats (fp32, C=64) ----------------
__global__ void k_bn_stats(const float* __restrict__ x, float* __restrict__ sum,
                           float* __restrict__ sumsq, int C, int rowsPerBlock) {
    int t = threadIdx.x;
    size_t base = (size_t)blockIdx.x * rowsPerBlock * C;
    size_t end  = base + (size_t)rowsPerBlock * C;
    float s0=0,q0=0;
    for (size_t f = base + t; f < end; f += 256) {
        float v = x[f]; s0 += v; q0 += v*v;
    }
    __shared__ float ls[256], lq[256];
    ls[t]=s0; lq[t]=q0;
    __syncthreads();
    if (t < C) {
        for (int j = t + C; j < 256; j += C) { s0 += ls[j]; q0 += lq[j]; }
        atomicAdd(&sum[t], s0); atomicAdd(&sumsq[t], q0);
    }
}

// ---------------- batchnorm stats (bf16, C=128/256/512) ----------------
__global__ void k_bn_stats_b(const bf16u* __restrict__ x, float* __restrict__ sum,
                             float* __restrict__ sumsq, int C, int rowsPerBlock) {
    int t = threadIdx.x;
    size_t base = (size_t)blockIdx.x * rowsPerBlock * C;
    size_t end  = base + (size_t)rowsPerBlock * C;
    if (C == 512) {
        float s0=0,q0=0,s1=0,q1=0;
        for (size_t f = base + t; f < end; f += 512) {
            float v = bf2f(x[f]);     s0 += v; q0 += v*v;
            float w = bf2f(x[f+256]); s1 += w; q1 += w*w;
        }
        atomicAdd(&sum[t], s0);      atomicAdd(&sumsq[t], q0);
        atomicAdd(&sum[t+256], s1);  atomicAdd(&sumsq[t+256], q1);
    } else {  // C <= 256
        float s0=0,q0=0;
        for (size_t f = base + t; f < end; f += 256) {
            float v = bf2f(x[f]); s0 += v; q0 += v*v;
        }
        atomicAdd(&sum[t & (C-1)], s0); atomicAdd(&sumsq[t & (C-1)], q0);
    }
}

// ---------------- BN1 apply: fp32 h1 -> bf16 mirror in ab[:,64:128] only ----------------
__global__ void k_bn_apply1(const float* __restrict__ h, const float* __restrict__ sum,
                            const float* __restrict__ sumsq, const float* __restrict__ g,
                            const float* __restrict__ b, bf16u* __restrict__ ab) {
    int idx = blockIdx.x * 256 + threadIdx.x;   // N*64
    int c = idx & 63, row = idx >> 6;
    const float invN = 1.0f / (float)N_;
    float mu  = sum[c] * invN;
    float var = sumsq[c] * invN - mu * mu;
    float v = (h[idx] - mu) * rsqrtf(var + EPSF) * g[c] + b[c];
    v = v > 0.f ? v : 0.f;
    ab[(size_t)row * 128 + 64 + c] = f2bf(v);
}

// ---------------- BN2 apply: bf16 pre -> bf16 post ----------------
__global__ void k_bn_apply2b(const bf16u* __restrict__ hp, const float* __restrict__ sum,
                             const float* __restrict__ sumsq, const float* __restrict__ g,
                             const float* __restrict__ b, bf16u* __restrict__ hb) {
    int idx = blockIdx.x * 256 + threadIdx.x;   // N*128
    int c = idx & 127;
    const float invN = 1.0f / (float)N_;
    float mu  = sum[c] * invN;
    float var = sumsq[c] * invN - mu * mu;
    float v = (bf2f(hp[idx]) - mu) * rsqrtf(var + EPSF) * g[c] + b[c];
    hb[idx] = f2bf(v > 0.f ? v : 0.f);
}

// ---------------- SAGE aggregate (mean) from bf16 mirror -> ab[:,0:64] ----------------
__global__ void k_sage_agg(const int* __restrict__ rows, const int* __restrict__ csr,
                           bf16u* __restrict__ ab) {
    int i = blockIdx.x * 4 + (threadIdx.x >> 6);
    int c = threadIdx.x & 63;
    int e0 = rows[i], e1 = rows[i+1];
    float s = 0.f;
    for (int e = e0; e < e1; ++e) s += bf2f(ab[(size_t)csr[e]*128 + 64 + c]);
    ab[(size_t)i*128 + c] = f2bf(s / fmaxf((float)(e1 - e0), 1.0f));
}

// ---------------- bf16 MFMA GEMM: C[n,m] = A[n,k]*BT[m,k]^T (+bias) ----------------
// 128x128 tile, BK=32, 4 waves x (4x4) mfma_f32_16x16x32_bf16 (layouts m89/m91/m120).
// Round-7: no reduction epilogues. Round-9: no permuted scatter-stores.
__global__ __launch_bounds__(256) void k_gemm_mfma(const bf16u* __restrict__ A,
                                                   const bf16u* __restrict__ BT,
                                                   const float* __restrict__ bias,
                                                   float* __restrict__ C,
                                                   int K, int M, int obf) {
    __shared__ bf16u As[128][40];
    __shared__ bf16u Bs[128][40];
    int tid = threadIdx.x;
    int wave = tid >> 6, lane = tid & 63;
    int wr = (wave >> 1) * 64, wc = (wave & 1) * 64;
    int row0 = blockIdx.y * 128, col0 = blockIdx.x * 128;
    f4v acc[4][4];
#pragma unroll
    for (int i = 0; i < 4; ++i)
#pragma unroll
        for (int j = 0; j < 4; ++j) acc[i][j] = (f4v)0.0f;

    int sr = tid >> 1;             // 0..127
    int sh = (tid & 1) * 16;       // k-half within BK
    int lr = lane & 15, lq = lane >> 4;

    for (int k0 = 0; k0 < K; k0 += 32) {
        const bf16u* ap = A + (size_t)(row0 + sr) * K + k0 + sh;
        *(uint4*)&As[sr][sh]     = *(const uint4*)ap;
        *(uint4*)&As[sr][sh + 8] = *(const uint4*)(ap + 8);
        const bf16u* bp = BT + (size_t)(col0 + sr) * K + k0 + sh;
        *(uint4*)&Bs[sr][sh]     = *(const uint4*)bp;
        *(uint4*)&Bs[sr][sh + 8] = *(const uint4*)(bp + 8);
        __syncthreads();
        s8v af[4], bfr[4];
#pragma unroll
        for (int i = 0; i < 4; ++i)
            af[i] = *(const s8v*)&As[wr + i*16 + lr][lq*8];
#pragma unroll
        for (int j = 0; j < 4; ++j)
            bfr[j] = *(const s8v*)&Bs[wc + j*16 + lr][lq*8];
#pragma unroll
        for (int i = 0; i < 4; ++i)
#pragma unroll
            for (int j = 0; j < 4; ++j)
                acc[i][j] = __builtin_amdgcn_mfma_f32_16x16x32_bf16(af[i], bfr[j], acc[i][j], 0, 0, 0);
        __syncthreads();
    }

    if (obf) {
        bf16u* Cb = (bf16u*)C;
#pragma unroll
        for (int i = 0; i < 4; ++i)
#pragma unroll
            for (int j = 0; j < 4; ++j) {
                int col = col0 + wc + j*16 + lr;
                float bv = bias ? bias[col] : 0.f;
#pragma unroll
                for (int r = 0; r < 4; ++r) {
                    int row = row0 + wr + i*16 + lq*4 + r;
                    Cb[(size_t)row * M + col] = f2bf(acc[i][j][r] + bv);
                }
            }
    } else {
#pragma unroll
        for (int i = 0; i < 4; ++i)
#pragma unroll
            for (int j = 0; j < 4; ++j) {
                int col = col0 + wc + j*16 + lr;
                float bv = bias ? bias[col] : 0.f;
#pragma unroll
                for (int r = 0; r < 4; ++r) {
                    int row = row0 + wr + i*16 + lq*4 + r;
                    C[(size_t)row * M + col] = acc[i][j][r] + bv;
                }
            }
    }
}

// ---------------- GAT attention coefficients: wave-per-node, channel-major hgat ----------------
__global__ __launch_bounds__(256) void k_gat_attn(const bf16u* __restrict__ hg,
                                                  const float* __restrict__ asrc,
                                                  const float* __restrict__ adst,
                                                  float* __restrict__ es,
                                                  float* __restrict__ ed) {
    int wave = threadIdx.x >> 6, lane = threadIdx.x & 63;
    int i = blockIdx.x * 4 + wave;
    const bf16u* hp = hg + (size_t)i*1024 + lane*16;   // 16 contig bf16: 4 channels x 4 heads
    float xc[4][4];    // [k][h], channel c = lane*4+k
#pragma unroll
    for (int k = 0; k < 4; ++k) {
        ushort4 u = *(const ushort4*)(hp + k*4);
        xc[k][0] = bf2f(u.x); xc[k][1] = bf2f(u.y);
        xc[k][2] = bf2f(u.z); xc[k][3] = bf2f(u.w);
    }
    float vs[4], vd[4];
#pragma unroll
    for (int h = 0; h < 4; ++h) {
        float4 a = *(const float4*)&asrc[h*256 + lane*4];
        float4 d = *(const float4*)&adst[h*256 + lane*4];
        vs[h] = xc[0][h]*a.x + xc[1][h]*a.y + xc[2][h]*a.z + xc[3][h]*a.w;
        vd[h] = xc[0][h]*d.x + xc[1][h]*d.y + xc[2][h]*d.z + xc[3][h]*d.w;
    }
#pragma unroll
    for (int off = 32; off > 0; off >>= 1) {
#pragma unroll
        for (int h = 0; h < 4; ++h) {
            vs[h] += __shfl_xor(vs[h], off, 64);
            vd[h] += __shfl_xor(vd[h], off, 64);
        }
    }
    if (lane == 0) {
        *(float4*)&es[i*4] = make_float4(vs[0], vs[1], vs[2], vs[3]);
        *(float4*)&ed[i*4] = make_float4(vd[0], vd[1], vd[2], vd[3]);
    }
}

// ---------------- per-node exact logit max (incl self-loop), wave-per-node ----------------
__global__ __launch_bounds__(256) void k_gat_max(const float* __restrict__ es,
                                                 const float* __restrict__ ed,
                                                 const int* __restrict__ rows,
                                                 const int* __restrict__ csr,
                                                 float* __restrict__ em) {
    int wave = threadIdx.x >> 6, lane = threadIdx.x & 63;
    int i = blockIdx.x * 4 + wave;
    float4 edv = *(const float4*)&ed[i*4];
    float4 sv = *(const float4*)&es[i*4];
    float e, m0, m1, m2, m3;
    e = sv.x + edv.x; m0 = e >= 0.f ? e : 0.2f*e;
    e = sv.y + edv.y; m1 = e >= 0.f ? e : 0.2f*e;
    e = sv.z + edv.z; m2 = e >= 0.f ? e : 0.2f*e;
    e = sv.w + edv.w; m3 = e >= 0.f ? e : 0.2f*e;
    int e0 = rows[i], e1 = rows[i+1];
    for (int ee = e0 + lane; ee < e1; ee += 64) {
        int s = csr[ee];
        float4 s2 = *(const float4*)&es[s*4];
        e = s2.x + edv.x; m0 = fmaxf(m0, e >= 0.f ? e : 0.2f*e);
        e = s2.y + edv.y; m1 = fmaxf(m1, e >= 0.f ? e : 0.2f*e);
        e = s2.z + edv.z; m2 = fmaxf(m2, e >= 0.f ? e : 0.2f*e);
        e = s2.w + edv.w; m3 = fmaxf(m3, e >= 0.f ? e : 0.2f*e);
    }
#pragma unroll
    for (int off = 32; off > 0; off >>= 1) {
        m0 = fmaxf(m0, __shfl_xor(m0, off, 64));
        m1 = fmaxf(m1, __shfl_xor(m1, off, 64));
        m2 = fmaxf(m2, __shfl_xor(m2, off, 64));
        m3 = fmaxf(m3, __shfl_xor(m3, off, 64));
    }
    if (lane == 0) *(float4*)&em[i*4] = make_float4(m0, m1, m2, m3);
}

// ---------------- GAT aggregate: single-pass softmax, ushort4 gather (round-10 proven) ----------------
// z stays in REGISTERS. Round-11 lesson: z-in-LDS via atomicAdd serialized 256
// threads on 4 shared words — 45.4 -> 55.3us. 4 VALU adds/edge is cheaper.
#define GCH 256
__global__ __launch_bounds__(256) void k_gat_agg(const bf16u* __restrict__ hg,
                                                 const float* __restrict__ es,
                                                 const float* __restrict__ ed,
                                                 const float* __restrict__ em,
                                                 const int* __restrict__ rows,
                                                 const int* __restrict__ csr,
                                                 const float* __restrict__ gbias,
                                                 bf16u* __restrict__ out) {
    __shared__ float4 se4[GCH];
    __shared__ int ssrc[GCH];
    int i = blockIdx.x, t = threadIdx.x;
    float4 edv = *(const float4*)&ed[i*4];
    float4 emv = *(const float4*)&em[i*4];
    float z0, z1, z2, z3, a0, a1, a2, a3;
    {
        float4 sv = *(const float4*)&es[i*4];
        float e;
        e = sv.x + edv.x; e = e >= 0.f ? e : 0.2f*e; z0 = __expf(e - emv.x);
        e = sv.y + edv.y; e = e >= 0.f ? e : 0.2f*e; z1 = __expf(e - emv.y);
        e = sv.z + edv.z; e = e >= 0.f ? e : 0.2f*e; z2 = __expf(e - emv.z);
        e = sv.w + edv.w; e = e >= 0.f ? e : 0.2f*e; z3 = __expf(e - emv.w);
        ushort4 u = *(const ushort4*)(hg + (size_t)i*1024 + t*4);
        a0 = z0 * bf2f(u.x); a1 = z1 * bf2f(u.y);
        a2 = z2 * bf2f(u.z); a3 = z3 * bf2f(u.w);
    }
    int e0 = rows[i], e1 = rows[i+1];
    for (int c0 = e0; c0 < e1; c0 += GCH) {
        int cn = min(GCH, e1 - c0);
        for (int j = t; j < cn; j += 256) {
            int s = csr[c0 + j];
            ssrc[j] = s;
            float4 sv = *(const float4*)&es[s*4];
            float4 v; float e;
            e = sv.x + edv.x; e = e >= 0.f ? e : 0.2f*e; v.x = __expf(e - emv.x);
            e = sv.y + edv.y; e = e >= 0.f ? e : 0.2f*e; v.y = __expf(e - emv.y);
            e = sv.z + edv.z; e = e >= 0.f ? e : 0.2f*e; v.z = __expf(e - emv.z);
            e = sv.w + edv.w; e = e >= 0.f ? e : 0.2f*e; v.w = __expf(e - emv.w);
            se4[j] = v;
        }
        __syncthreads();
        for (int j = 0; j < cn; ++j) {
            float4 ex = se4[j];
            ushort4 u = *(const ushort4*)(hg + (size_t)ssrc[j]*1024 + t*4);
            z0 += ex.x; a0 += ex.x * bf2f(u.x);
            z1 += ex.y; a1 += ex.y * bf2f(u.y);
            z2 += ex.z; a2 += ex.z * bf2f(u.z);
            z3 += ex.w; a3 += ex.w * bf2f(u.w);
        }
        __syncthreads();
    }
    float o = 0.25f * (a0/z0 + a1/z1 + a2/z2 + a3/z3);
    out[(size_t)i*256 + t] = f2bf(o + gbias[t]);
}

// ---------------- layer 4: fused BN3+ReLU + GCN aggregate (wave-per-node, ushort4) ----------------
__global__ __launch_bounds__(256) void k_gcn4_agg(const bf16u* __restrict__ h3b,
                                                  const float* __restrict__ dis,
                                                  const int* __restrict__ rows,
                                                  const int* __restrict__ csr,
                                                  const float* __restrict__ sum,
                                                  const float* __restrict__ sumsq,
                                                  const float* __restrict__ g,
                                                  const float* __restrict__ b,
                                                  bf16u* __restrict__ xab) {
    int wave = threadIdx.x >> 6, q = threadIdx.x & 63;
    int i = blockIdx.x * 4 + wave;
    int c = q * 4;
    const float invN = 1.0f / (float)N_;
    float4 sm = *(const float4*)&sum[c];
    float4 sq = *(const float4*)&sumsq[c];
    float4 gg = *(const float4*)&g[c];
    float4 bb = *(const float4*)&b[c];
    float mu, sc0, sc1, sc2, sc3, sh0, sh1, sh2, sh3;
    mu = sm.x*invN; sc0 = rsqrtf(sq.x*invN - mu*mu + EPSF)*gg.x; sh0 = bb.x - mu*sc0;
    mu = sm.y*invN; sc1 = rsqrtf(sq.y*invN - mu*mu + EPSF)*gg.y; sh1 = bb.y - mu*sc1;
    mu = sm.z*invN; sc2 = rsqrtf(sq.z*invN - mu*mu + EPSF)*gg.z; sh2 = bb.z - mu*sc2;
    mu = sm.w*invN; sc3 = rsqrtf(sq.w*invN - mu*mu + EPSF)*gg.w; sh3 = bb.w - mu*sc3;
    float di = dis[i];
    float a0, a1, a2, a3;
    {
        ushort4 u = *(const ushort4*)(h3b + (size_t)i*256 + c);
        float v, dd = di * di;
        v = fmaf(bf2f(u.x), sc0, sh0); v = v > 0.f ? v : 0.f; a0 = v * dd;
        v = fmaf(bf2f(u.y), sc1, sh1); v = v > 0.f ? v : 0.f; a1 = v * dd;
        v = fmaf(bf2f(u.z), sc2, sh2); v = v > 0.f ? v : 0.f; a2 = v * dd;
        v = fmaf(bf2f(u.w), sc3, sh3); v = v > 0.f ? v : 0.f; a3 = v * dd;
    }
    int e0 = rows[i], e1 = rows[i+1];
    for (int e = e0; e < e1; ++e) {
        int s = csr[e];
        float w = dis[s] * di;
        ushort4 u = *(const ushort4*)(h3b + (size_t)s*256 + c);
        float v;
        v = fmaf(bf2f(u.x), sc0, sh0); v = v > 0.f ? v : 0.f; a0 += v * w;
        v = fmaf(bf2f(u.y), sc1, sh1); v = v > 0.f ? v : 0.f; a1 += v * w;
        v = fmaf(bf2f(u.z), sc2, sh2); v = v > 0.f ? v : 0.f; a2 += v * w;
        v = fmaf(bf2f(u.w), sc3, sh3); v = v > 0.f ? v : 0.f; a3 += v * w;
    }
    ushort4 o;
    o.x = f2bf(a0); o.y = f2bf(a1); o.z = f2bf(a2); o.w = f2bf(a3);
    *(ushort4*)(xab + (size_t)i*256 + c) = o;
}

// ---------------- pooling with fused BN4+ReLU ----------------
__global__ void k_pool(const bf16u* __restrict__ h4b, const int* __restrict__ gb,
                       const float* __restrict__ sum, const float* __restrict__ sumsq,
                       const float* __restrict__ g, const float* __restrict__ b,
                       float* __restrict__ pooled) {
    int gi = blockIdx.y;
    int t = threadIdx.x;
    const float invN = 1.0f / (float)N_;
    float mu0 = sum[t] * invN;
    float sc0 = rsqrtf(sumsq[t] * invN - mu0*mu0 + EPSF) * g[t];
    float sh0 = b[t] - mu0 * sc0;
    float mu1 = sum[t+256] * invN;
    float sc1 = rsqrtf(sumsq[t+256] * invN - mu1*mu1 + EPSF) * g[t+256];
    float sh1 = b[t+256] - mu1 * sc1;
    int r0g = gb[gi], r1g = gb[gi+1];
    int n = r1g - r0g;
    if (n <= 0) return;
    int per = (n + 15) >> 4;
    int r0 = r0g + blockIdx.x * per;
    int r1 = min(r0 + per, r1g);
    if (r0 >= r1) return;
    float s0=0.f, s1=0.f, m0=0.f, m1=0.f;   // post-ReLU >= 0: max init 0 valid
    for (int r = r0; r < r1; ++r) {
        float v = fmaf(bf2f(h4b[(size_t)r*512 + t]), sc0, sh0);
        v = v > 0.f ? v : 0.f;
        s0 += v; m0 = fmaxf(m0, v);
        float w = fmaf(bf2f(h4b[(size_t)r*512 + 256 + t]), sc1, sh1);
        w = w > 0.f ? w : 0.f;
        s1 += w; m1 = fmaxf(m1, w);
    }
    atomicAdd(&pooled[gi*1024 + t], s0);
    atomicAdd(&pooled[gi*1024 + 256 + t], s1);
    atomicMax((int*)&pooled[gi*1024 + 512 + t],  __float_as_int(m0));
    atomicMax((int*)&pooled[gi*1024 + 768 + t],  __float_as_int(m1));
}

// ---------------- FC (K-split, float4, atomic reduce; mean-scale folded in) ----------------
#define FCKZ 16
#define FCKC (1024 / FCKZ)   // 64

__global__ void k_fc_init(const float* __restrict__ b, float* __restrict__ out) {
    int i = blockIdx.x * 256 + threadIdx.x;   // 32*1024
    out[i] = b[i & 1023];
}

__global__ __launch_bounds__(256) void k_fc2(const float* __restrict__ pooled,
                                             const float* __restrict__ w,
                                             const int* __restrict__ gb,
                                             float* __restrict__ out) {
    __shared__ float pr[FCKC];
    int g = blockIdx.x;
    int z = blockIdx.y;
    int t = threadIdx.x;
    int k0 = z * FCKC;
    if (t < FCKC) {
        float scale = (z < 8) ? 1.0f / fmaxf((float)(gb[g+1] - gb[g]), 1.0f) : 1.0f;
        pr[t] = pooled[g * 1024 + k0 + t] * scale;   // mean part needs 1/cnt
    }
    __syncthreads();
    int m0 = t * 4;
    float ax = 0.f, ay = 0.f, az = 0.f, aw = 0.f;
#pragma unroll 8
    for (int k = 0; k < FCKC; ++k) {
        const float4 wv = *(const float4*)&w[(size_t)(k0 + k) * 1024 + m0];
        float p = pr[k];
        ax += p * wv.x; ay += p * wv.y; az += p * wv.z; aw += p * wv.w;
    }
    atomicAdd(&out[g * 1024 + m0 + 0], ax);
    atomicAdd(&out[g * 1024 + m0 + 1], ay);
    atomicAdd(&out[g * 1024 + m0 + 2], az);
    atomicAdd(&out[g * 1024 + m0 + 3], aw);
}

// ---------------- host ----------------
extern "C" void kernel_launch(void* const* d_in, const int* in_sizes, int n_in,
                              void* d_out, int out_size, void* d_ws, size_t ws_size,
                              hipStream_t stream) {
    (void)in_sizes; (void)n_in; (void)out_size; (void)ws_size;
    const float* x       = (const float*)d_in[0];
    const int*   ei      = (const int*)d_in[1];
    const int*   batch   = (const int*)d_in[2];
    const float* gcn1_w  = (const float*)d_in[3];
    const float* gcn1_b  = (const float*)d_in[4];
    const float* sage_wl = (const float*)d_in[5];
    const float* sage_wr = (const float*)d_in[6];
    const float* sage_b  = (const float*)d_in[7];
    const float* gat_w   = (const float*)d_in[8];
    const float* gat_as  = (const float*)d_in[9];
    const float* gat_ad  = (const float*)d_in[10];
    const float* gat_b   = (const float*)d_in[11];
    const float* gcn4_w  = (const float*)d_in[12];
    const float* gcn4_b  = (const float*)d_in[13];
    const float* bn1_g   = (const float*)d_in[14];
    const float* bn1_b   = (const float*)d_in[15];
    const float* bn2_g   = (const float*)d_in[16];
    const float* bn2_b   = (const float*)d_in[17];
    const float* bn3_g   = (const float*)d_in[18];
    const float* bn3_b   = (const float*)d_in[19];
    const float* bn4_g   = (const float*)d_in[20];
    const float* bn4_b   = (const float*)d_in[21];
    const float* fc_w    = (const float*)d_in[22];
    const float* fc_b    = (const float*)d_in[23];
    float* out = (float*)d_out;

    char* w8 = (char*)d_ws;
    int*   indeg  = (int*)(w8 + OFF_INDEG);
    int*   rows   = (int*)(w8 + OFF_ROWS);
    int*   cursor = (int*)(w8 + OFF_CURSOR);
    int*   csr    = (int*)(w8 + OFF_CSR);
    float* dis    = (float*)(w8 + OFF_DIS);
    float* es     = (float*)(w8 + OFF_ES);
    float* ed     = (float*)(w8 + OFF_ED);
    float* bns    = (float*)(w8 + OFF_BNS);   // [4][512] per-layer slices
    float* bnq    = (float*)(w8 + OFF_BNQ);
    int*   gb     = (int*)(w8 + OFF_GB);
    float* pooled = (float*)(w8 + OFF_POOL);
    float* h1     = (float*)(w8 + OFF_H1);
    bf16u* ab     = (bf16u*)(w8 + OFF_AB);
    bf16u* h2p    = (bf16u*)(w8 + OFF_H2P);
    bf16u* h2b    = (bf16u*)(w8 + OFF_H2B);
    bf16u* h3b    = (bf16u*)(w8 + OFF_H3B);
    bf16u* hgat   = (bf16u*)(w8 + OFF_HGAT);
    bf16u* xa4b   = (bf16u*)(w8 + OFF_XA4B);
    bf16u* wT1    = (bf16u*)(w8 + OFF_WT1);
    bf16u* wT2    = (bf16u*)(w8 + OFF_WT2);
    bf16u* wT3    = (bf16u*)(w8 + OFF_WT3);
    bf16u* h4b    = (bf16u*)(w8 + OFF_H4B);
    float* em     = (float*)(w8 + OFF_EM);

    const int* srcE = ei;        // edge_index[0,:]
    const int* dstE = ei + E_;   // edge_index[1,:]

    const int BNB = 512;
    const int BNR = N_ / BNB;

    // ---- setup: ONE memset zeroes indeg..pooled ----
    hipMemsetAsync(w8, 0, OFF_XA1, stream);
    k_indeg<<<E_/256, 256, 0, stream>>>(dstE, indeg);
    k_scan<<<1, 1024, 0, stream>>>(indeg, rows, cursor, dis);
    k_fill<<<E_/256, 256, 0, stream>>>(srcE, dstE, cursor, csr);
    k_wconv_all<<<1089, 256, 0, stream>>>(gat_w, gcn4_w, sage_wl, sage_wr, batch,
                                          wT1, wT2, wT3, gb);

    // ---- layer 1: fused GCN 5->64 (agg+matmul), BN, ReLU (bf16 mirror only) ----
    k_gcn1<<<N_/4, 256, 0, stream>>>(x, dis, rows, csr, gcn1_w, gcn1_b, h1);
    k_bn_stats<<<BNB, 256, 0, stream>>>(h1, bns, bnq, 64, BNR);
    k_bn_apply1<<<(N_*64)/256, 256, 0, stream>>>(h1, bns, bnq, bn1_g, bn1_b, ab);

    // ---- layer 2: SAGE 64->128 via single MFMA GEMM on [agg|h1], BN, ReLU ----
    k_sage_agg<<<N_/4, 256, 0, stream>>>(rows, csr, ab);
    {
        dim3 grid(1, N_/128);
        k_gemm_mfma<<<grid, 256, 0, stream>>>(ab, wT3, sage_b, (float*)h2p, 128, 128, 1);
    }
    k_bn_stats_b<<<BNB, 256, 0, stream>>>(h2p, bns + 512, bnq + 512, 128, BNR);
    k_bn_apply2b<<<(N_*128)/256, 256, 0, stream>>>(h2p, bns + 512, bnq + 512, bn2_g, bn2_b, h2b);

    // ---- layer 3: GAT GEMM (weight-permuted -> channel-major out), attention, max, aggregate ----
    {
        dim3 grid(1024/128, N_/128);
        k_gemm_mfma<<<grid, 256, 0, stream>>>(h2b, wT1, nullptr, (float*)hgat, 128, 1024, 1);
    }
    k_gat_attn<<<N_/4, 256, 0, stream>>>(hgat, gat_as, gat_ad, es, ed);
    k_gat_max<<<N_/4, 256, 0, stream>>>(es, ed, rows, csr, em);
    k_gat_agg<<<N_, 256, 0, stream>>>(hgat, es, ed, em, rows, csr, gat_b, h3b);
    k_bn_stats_b<<<BNB, 256, 0, stream>>>(h3b, bns + 1024, bnq + 1024, 256, BNR);

    // ---- layer 4: fused BN3+ReLU+aggregate, MFMA GEMM 256->512 (bf16 out) ----
    k_gcn4_agg<<<N_/4, 256, 0, stream>>>(h3b, dis, rows, csr, bns + 1024, bnq + 1024,
                                         bn3_g, bn3_b, xa4b);
    {
        dim3 grid(512/128, N_/128);
        k_gemm_mfma<<<grid, 256, 0, stream>>>(xa4b, wT2, gcn4_b, (float*)h4b, 256, 512, 1);
    }
    k_bn_stats_b<<<BNB, 256, 0, stream>>>(h4b, bns + 1536, bnq + 1536, 512, BNR);

    // ---- pooling with fused BN4+ReLU -> [32,1024] (mean scale folded into FC) ----
    {
        dim3 grid(16, G_);
        k_pool<<<grid, 256, 0, stream>>>(h4b, gb, bns + 1536, bnq + 1536, bn4_g, bn4_b, pooled);
    }

    // ---- FC 1024->1024 ----
    k_fc_init<<<(G_*1024)/256, 256, 0, stream>>>(fc_b, out);
    {
        dim3 grid(G_, FCKZ);
        k_fc2<<<grid, 256, 0, stream>>>(pooled, fc_w, gb, out);
    }
}

// Round 13
// 402.816 us; speedup vs baseline: 1.0289x; 1.0147x over previous
//
#include <hip/hip_runtime.h>

#define N_ 16384
#define E_ 131072
#define G_ 32
#define EPSF 1e-5f

typedef unsigned short bf16u;
typedef __attribute__((ext_vector_type(8))) short s8v;   // 8 bf16 (4 VGPRs)
typedef __attribute__((ext_vector_type(4))) float f4v;   // 4 fp32 acc

__device__ __forceinline__ bf16u f2bf(float v) {
    union { float f; unsigned u; } x; x.f = v;
    unsigned r = x.u + 0x7FFF + ((x.u >> 16) & 1);   // RNE
    return (bf16u)(r >> 16);
}
__device__ __forceinline__ float bf2f(bf16u u) {
    union { unsigned u; float f; } x; x.u = (unsigned)u << 16;
    return x.f;
}

// ---------------- workspace layout (bytes) ----------------
static const size_t OFF_INDEG = 0;          // int[N]        } single
static const size_t OFF_ROWS  = 65536;      // int[N+1]      } memset
static const size_t OFF_CURSOR= 131584;     // int[N]        } covers
static const size_t OFF_CSR   = 197120;     // int[E]        } 0..OFF_XA1
static const size_t OFF_DIS   = 721408;     // float[N]
static const size_t OFF_ES    = 786944;     // float[4N]
static const size_t OFF_ED    = 1049088;    // float[4N]
static const size_t OFF_BNS   = 1311232;    // float[4][512]
static const size_t OFF_BNQ   = 1319424;    // float[4][512]
static const size_t OFF_GB    = 1327616;    // int[33]
static const size_t OFF_POOL  = 1327872;    // float[32*1024]
static const size_t OFF_XA1   = 1458944;    // (memset end marker)
static const size_t OFF_H1    = 1786624;    // float[64N]   4 MB
static const size_t OFF_AB    = 5980928;    // bf16[128N]   4 MB ([agg|h1] concat)
static const size_t OFF_H2P   = 10175232;   // bf16[128N]   4 MB (pre-BN)
static const size_t OFF_H2B   = 14369536;   // bf16[128N]   4 MB (post-BN)
static const size_t OFF_H3B   = 18563840;   // bf16[256N]   8 MB
static const size_t OFF_HGAT  = 35328768;   // bf16[1024N]  32 MB (channel-major [node][c*4+h])
static const size_t OFF_XA4B  = OFF_HGAT;   // bf16[256N] 8 MB (hgat dead by then)
static const size_t OFF_WT1   = 68883200;   // bf16[1024*128] (row-PERMUTED gat_w^T)
static const size_t OFF_WT2   = 69145344;   // bf16[512*256]
static const size_t OFF_WT3   = 69407488;   // bf16[128*128]
static const size_t OFF_H4B   = 69440256;   // bf16[512N] 16 MB
static const size_t OFF_EM    = 86217472;   // float[4N] per-node logit max
static const size_t OFF_VES   = 86479616;   // float[4][128]  W_h·a_src_h
static const size_t OFF_VED   = 86481664;   // float[4][128]  W_h·a_dst_h
// total ≈ 86.5 MB

// scan + fused dis + cursor copy
__global__ __launch_bounds__(1024) void k_scan(const int* __restrict__ indeg,
                                               int* __restrict__ rows,
                                               int* __restrict__ cursor,
                                               float* __restrict__ dis) {
    __shared__ int part[1024];
    int t = threadIdx.x;
    int base = t * 16;
    int local[16];
    int s = 0;
#pragma unroll
    for (int i = 0; i < 16; ++i) {
        local[i] = indeg[base + i]; s += local[i];
        dis[base + i] = rsqrtf((float)local[i] + 1.0f);
    }
    part[t] = s;
    __syncthreads();
    for (int off = 1; off < 1024; off <<= 1) {
        int v = (t >= off) ? part[t - off] : 0;
        __syncthreads();
        part[t] += v;
        __syncthreads();
    }
    int run = (t == 0) ? 0 : part[t - 1];
#pragma unroll
    for (int i = 0; i < 16; ++i) {
        rows[base + i] = run; cursor[base + i] = run; run += local[i];
    }
    if (t == 1023) rows[N_] = run;
}

__global__ void k_fill(const int* __restrict__ src, const int* __restrict__ dst,
                       int* __restrict__ cursor, int* __restrict__ csr) {
    int e = blockIdx.x * 256 + threadIdx.x;
    if (e < E_) {
        int p = atomicAdd(&cursor[dst[e]], 1);
        csr[p] = src[e];
    }
}

// ------- fused setup: weight transpose/convert + gbounds + v_es/v_ed + indeg -------
// wT1 rows PERMUTED (m' = c*4+h -> source col h*256+c): round-9 lesson — permute
// the weight, never scatter-store the 32 MB output.
// v_es[h][k] = sum_c gat_w[k][h*256+c]*asrc[h][c]: attention-by-associativity —
// lets es/ed be computed from h2b (4 MB) instead of hgat (32 MB).
__global__ void k_wconv_all(const float* __restrict__ gat_w,
                            const float* __restrict__ gcn4_w,
                            const float* __restrict__ wl, const float* __restrict__ wr,
                            const int* __restrict__ batch,
                            const float* __restrict__ gat_as,
                            const float* __restrict__ gat_ad,
                            const int* __restrict__ dstE,
                            bf16u* __restrict__ wT1, bf16u* __restrict__ wT2,
                            bf16u* __restrict__ wT3, int* __restrict__ gb,
                            float* __restrict__ ves, float* __restrict__ ved,
                            int* __restrict__ indeg) {
    int idx = blockIdx.x * 256 + threadIdx.x;
    if (idx < 131072) {          // gat_w [128][1024] -> wT1[m'=c*4+h][128]
        int m = idx >> 7, k = idx & 127;
        int col = (m & 3) * 256 + (m >> 2);     // h = m&3, c = m>>2
        wT1[idx] = f2bf(gat_w[(size_t)k * 1024 + col]);
    } else if (idx < 262144) {   // gcn4_w [256][512] -> wT2[512][256]
        int j = idx - 131072;
        int m = j >> 8, k = j & 255;
        wT2[j] = f2bf(gcn4_w[(size_t)k * 512 + m]);
    } else if (idx < 278528) {   // [wl;wr] -> wT3[128][128]
        int j = idx - 262144;
        int m = j >> 7, k = j & 127;
        float v = (k < 64) ? wl[k*128 + m] : wr[(k-64)*128 + m];
        wT3[j] = f2bf(v);
    } else if (idx < 278592) {   // graph-batch bounds
        int g = idx - 278528;
        if (g > G_) return;
        if (g == G_) { gb[G_] = N_; return; }
        int lo = 0, hi = N_;
        while (lo < hi) { int mid = (lo + hi) >> 1; if (batch[mid] < g) lo = mid + 1; else hi = mid; }
        gb[g] = lo;
    } else if (idx < 279104) {   // v_es (4 heads x 128 k)
        int j = idx - 278592;
        int h = j >> 7, k = j & 127;
        float s = 0.f;
        for (int c = 0; c < 256; ++c)
            s += gat_w[(size_t)k * 1024 + h*256 + c] * gat_as[h*256 + c];
        ves[j] = s;
    } else if (idx < 279616) {   // v_ed
        int j = idx - 279104;
        int h = j >> 7, k = j & 127;
        float s = 0.f;
        for (int c = 0; c < 256; ++c)
            s += gat_w[(size_t)k * 1024 + h*256 + c] * gat_ad[h*256 + c];
        ved[j] = s;
    } else if (idx < 410688) {   // indeg (was k_indeg)
        int e = idx - 279616;
        atomicAdd(&indeg[dstE[e]], 1);
    }
}

// ---------------- layer 1: fused GCN aggregate(5) + matmul(5->64), wave-per-node ----------------
__global__ __launch_bounds__(256) void k_gcn1(const float* __restrict__ x,
                                              const float* __restrict__ dis,
                                              const int* __restrict__ rows,
                                              const int* __restrict__ csr,
                                              const float* __restrict__ w,
                                              const float* __restrict__ b,
                                              float* __restrict__ h1) {
    int wave = threadIdx.x >> 6, lane = threadIdx.x & 63;
    int i = blockIdx.x * 4 + wave;
    float a0=0,a1=0,a2=0,a3=0,a4=0;
    int e0 = rows[i], e1 = rows[i+1];
    for (int e = e0 + lane; e < e1; e += 64) {
        int s = csr[e];
        float wt = dis[s];
        a0 += x[s*5+0]*wt; a1 += x[s*5+1]*wt; a2 += x[s*5+2]*wt;
        a3 += x[s*5+3]*wt; a4 += x[s*5+4]*wt;
    }
#pragma unroll
    for (int off = 32; off > 0; off >>= 1) {
        a0 += __shfl_xor(a0, off, 64); a1 += __shfl_xor(a1, off, 64);
        a2 += __shfl_xor(a2, off, 64); a3 += __shfl_xor(a3, off, 64);
        a4 += __shfl_xor(a4, off, 64);
    }
    float di = dis[i];
    float xa0 = di*(a0 + di*x[i*5+0]);
    float xa1v = di*(a1 + di*x[i*5+1]);
    float xa2 = di*(a2 + di*x[i*5+2]);
    float xa3 = di*(a3 + di*x[i*5+3]);
    float xa4 = di*(a4 + di*x[i*5+4]);
    float hv = b[lane] + xa0*w[lane] + xa1v*w[64+lane] + xa2*w[128+lane]
             + xa3*w[192+lane] + xa4*w[256+lane];
    h1[(size_t)i*64 + lane] = hv;
}

// ---------------- batchnorm stats (fp32, C=64) ----------------
__global__ void k_bn_stats(const float* __restrict__ x, float* __restrict__ sum,
                           float* __restrict__ sumsq, int C, int rowsPerBlock) {
    int t = threadIdx.x;
    size_t base = (size_t)blockIdx.x * rowsPerBlock * C;
    size_t end  = base + (size_t)rowsPerBlock * C;
    float s0=0,q0=0;
    for (size_t f = base + t; f < end; f += 256) {
        float v = x[f]; s0 += v; q0 += v*v;
    }
    __shared__ float ls[256], lq[256];
    ls[t]=s0; lq[t]=q0;
    __syncthreads();
    if (t < C) {
        for (int j = t + C; j < 256; j += C) { s0 += ls[j]; q0 += lq[j]; }
        atomicAdd(&sum[t], s0); atomicAdd(&sumsq[t], q0);
    }
}

// ---------------- batchnorm stats (bf16, C=128/256/512) ----------------
__global__ void k_bn_stats_b(const bf16u* __restrict__ x, float* __restrict__ sum,
                             float* __restrict__ sumsq, int C, int rowsPerBlock) {
    int t = threadIdx.x;
    size_t base = (size_t)blockIdx.x * rowsPerBlock * C;
    size_t end  = base + (size_t)rowsPerBlock * C;
    if (C == 512) {
        float s0=0,q0=0,s1=0,q1=0;
        for (size_t f = base + t; f < end; f += 512) {
            float v = bf2f(x[f]);     s0 += v; q0 += v*v;
            float w = bf2f(x[f+256]); s1 += w; q1 += w*w;
        }
        atomicAdd(&sum[t], s0);      atomicAdd(&sumsq[t], q0);
        atomicAdd(&sum[t+256], s1);  atomicAdd(&sumsq[t+256], q1);
    } else {  // C <= 256
        float s0=0,q0=0;
        for (size_t f = base + t; f < end; f += 256) {
            float v = bf2f(x[f]); s0 += v; q0 += v*v;
        }
        atomicAdd(&sum[t & (C-1)], s0); atomicAdd(&sumsq[t & (C-1)], q0);
    }
}

// ---------------- BN1 apply: fp32 h1 -> bf16 mirror in ab[:,64:128] only ----------------
__global__ void k_bn_apply1(const float* __restrict__ h, const float* __restrict__ sum,
                            const float* __restrict__ sumsq, const float* __restrict__ g,
                            const float* __restrict__ b, bf16u* __restrict__ ab) {
    int idx = blockIdx.x * 256 + threadIdx.x;   // N*64
    int c = idx & 63, row = idx >> 6;
    const float invN = 1.0f / (float)N_;
    float mu  = sum[c] * invN;
    float var = sumsq[c] * invN - mu * mu;
    float v = (h[idx] - mu) * rsqrtf(var + EPSF) * g[c] + b[c];
    v = v > 0.f ? v : 0.f;
    ab[(size_t)row * 128 + 64 + c] = f2bf(v);
}

// ---------------- BN2 apply + fused GAT attention coefficients (wave-per-node) ----------------
// es[i,h] = h2b[i,:]·v_es[h] (associativity: (A·W)·a = A·(W·a)) — reads 4 MB h2p
// instead of 32 MB hgat; replaces the old standalone k_gat_attn pass entirely.
__global__ __launch_bounds__(256) void k_bn_apply2b_attn(
        const bf16u* __restrict__ hp, const float* __restrict__ sum,
        const float* __restrict__ sumsq, const float* __restrict__ g,
        const float* __restrict__ b, const float* __restrict__ ves,
        const float* __restrict__ ved, bf16u* __restrict__ hb,
        float* __restrict__ es, float* __restrict__ ed) {
    int wave = threadIdx.x >> 6, lane = threadIdx.x & 63;
    int i = blockIdx.x * 4 + wave;
    int c = lane * 2;
    const float invN = 1.0f / (float)N_;
    float2 sm = *(const float2*)&sum[c];
    float2 sq = *(const float2*)&sumsq[c];
    float2 gg = *(const float2*)&g[c];
    float2 bb = *(const float2*)&b[c];
    float mu0 = sm.x*invN, mu1 = sm.y*invN;
    float sc0 = rsqrtf(sq.x*invN - mu0*mu0 + EPSF)*gg.x, sh0 = bb.x - mu0*sc0;
    float sc1 = rsqrtf(sq.y*invN - mu1*mu1 + EPSF)*gg.y, sh1 = bb.y - mu1*sc1;
    unsigned pv = *(const unsigned*)&hp[(size_t)i*128 + c];
    float v0 = bf2f((bf16u)(pv & 0xFFFF));
    float v1 = bf2f((bf16u)(pv >> 16));
    v0 = fmaf(v0, sc0, sh0); v0 = v0 > 0.f ? v0 : 0.f;
    v1 = fmaf(v1, sc1, sh1); v1 = v1 > 0.f ? v1 : 0.f;
    unsigned ow = (unsigned)f2bf(v0) | ((unsigned)f2bf(v1) << 16);
    *(unsigned*)&hb[(size_t)i*128 + c] = ow;
    float vs[4], vd[4];
#pragma unroll
    for (int h = 0; h < 4; ++h) {
        float2 a = *(const float2*)&ves[h*128 + c];
        float2 d = *(const float2*)&ved[h*128 + c];
        vs[h] = v0*a.x + v1*a.y;
        vd[h] = v0*d.x + v1*d.y;
    }
#pragma unroll
    for (int off = 32; off > 0; off >>= 1) {
#pragma unroll
        for (int h = 0; h < 4; ++h) {
            vs[h] += __shfl_xor(vs[h], off, 64);
            vd[h] += __shfl_xor(vd[h], off, 64);
        }
    }
    if (lane == 0) {
        *(float4*)&es[i*4] = make_float4(vs[0], vs[1], vs[2], vs[3]);
        *(float4*)&ed[i*4] = make_float4(vd[0], vd[1], vd[2], vd[3]);
    }
}

// ---------------- SAGE aggregate (mean) from bf16 mirror -> ab[:,0:64] ----------------
__global__ void k_sage_agg(const int* __restrict__ rows, const int* __restrict__ csr,
                           bf16u* __restrict__ ab) {
    int i = blockIdx.x * 4 + (threadIdx.x >> 6);
    int c = threadIdx.x & 63;
    int e0 = rows[i], e1 = rows[i+1];
    float s = 0.f;
    for (int e = e0; e < e1; ++e) s += bf2f(ab[(size_t)csr[e]*128 + 64 + c]);
    ab[(size_t)i*128 + c] = f2bf(s / fmaxf((float)(e1 - e0), 1.0f));
}

// ---------------- bf16 MFMA GEMM: C[n,m] = A[n,k]*BT[m,k]^T (+bias) ----------------
// 128x128 tile, BK=32, 4 waves x (4x4) mfma_f32_16x16x32_bf16 (layouts m89/m91/m120).
// Round-7: no reduction epilogues. Round-9: no permuted scatter-stores.
__global__ __launch_bounds__(256) void k_gemm_mfma(const bf16u* __restrict__ A,
                                                   const bf16u* __restrict__ BT,
                                                   const float* __restrict__ bias,
                                                   float* __restrict__ C,
                                                   int K, int M, int obf) {
    __shared__ bf16u As[128][40];
    __shared__ bf16u Bs[128][40];
    int tid = threadIdx.x;
    int wave = tid >> 6, lane = tid & 63;
    int wr = (wave >> 1) * 64, wc = (wave & 1) * 64;
    int row0 = blockIdx.y * 128, col0 = blockIdx.x * 128;
    f4v acc[4][4];
#pragma unroll
    for (int i = 0; i < 4; ++i)
#pragma unroll
        for (int j = 0; j < 4; ++j) acc[i][j] = (f4v)0.0f;

    int sr = tid >> 1;             // 0..127
    int sh = (tid & 1) * 16;       // k-half within BK
    int lr = lane & 15, lq = lane >> 4;

    for (int k0 = 0; k0 < K; k0 += 32) {
        const bf16u* ap = A + (size_t)(row0 + sr) * K + k0 + sh;
        *(uint4*)&As[sr][sh]     = *(const uint4*)ap;
        *(uint4*)&As[sr][sh + 8] = *(const uint4*)(ap + 8);
        const bf16u* bp = BT + (size_t)(col0 + sr) * K + k0 + sh;
        *(uint4*)&Bs[sr][sh]     = *(const uint4*)bp;
        *(uint4*)&Bs[sr][sh + 8] = *(const uint4*)(bp + 8);
        __syncthreads();
        s8v af[4], bfr[4];
#pragma unroll
        for (int i = 0; i < 4; ++i)
            af[i] = *(const s8v*)&As[wr + i*16 + lr][lq*8];
#pragma unroll
        for (int j = 0; j < 4; ++j)
            bfr[j] = *(const s8v*)&Bs[wc + j*16 + lr][lq*8];
#pragma unroll
        for (int i = 0; i < 4; ++i)
#pragma unroll
            for (int j = 0; j < 4; ++j)
                acc[i][j] = __builtin_amdgcn_mfma_f32_16x16x32_bf16(af[i], bfr[j], acc[i][j], 0, 0, 0);
        __syncthreads();
    }

    if (obf) {
        bf16u* Cb = (bf16u*)C;
#pragma unroll
        for (int i = 0; i < 4; ++i)
#pragma unroll
            for (int j = 0; j < 4; ++j) {
                int col = col0 + wc + j*16 + lr;
                float bv = bias ? bias[col] : 0.f;
#pragma unroll
                for (int r = 0; r < 4; ++r) {
                    int row = row0 + wr + i*16 + lq*4 + r;
                    Cb[(size_t)row * M + col] = f2bf(acc[i][j][r] + bv);
                }
            }
    } else {
#pragma unroll
        for (int i = 0; i < 4; ++i)
#pragma unroll
            for (int j = 0; j < 4; ++j) {
                int col = col0 + wc + j*16 + lr;
                float bv = bias ? bias[col] : 0.f;
#pragma unroll
                for (int r = 0; r < 4; ++r) {
                    int row = row0 + wr + i*16 + lq*4 + r;
                    C[(size_t)row * M + col] = acc[i][j][r] + bv;
                }
            }
    }
}

// ---------------- per-node exact logit max (incl self-loop), wave-per-node ----------------
__global__ __launch_bounds__(256) void k_gat_max(const float* __restrict__ es,
                                                 const float* __restrict__ ed,
                                                 const int* __restrict__ rows,
                                                 const int* __restrict__ csr,
                                                 float* __restrict__ em) {
    int wave = threadIdx.x >> 6, lane = threadIdx.x & 63;
    int i = blockIdx.x * 4 + wave;
    float4 edv = *(const float4*)&ed[i*4];
    float4 sv = *(const float4*)&es[i*4];
    float e, m0, m1, m2, m3;
    e = sv.x + edv.x; m0 = e >= 0.f ? e : 0.2f*e;
    e = sv.y + edv.y; m1 = e >= 0.f ? e : 0.2f*e;
    e = sv.z + edv.z; m2 = e >= 0.f ? e : 0.2f*e;
    e = sv.w + edv.w; m3 = e >= 0.f ? e : 0.2f*e;
    int e0 = rows[i], e1 = rows[i+1];
    for (int ee = e0 + lane; ee < e1; ee += 64) {
        int s = csr[ee];
        float4 s2 = *(const float4*)&es[s*4];
        e = s2.x + edv.x; m0 = fmaxf(m0, e >= 0.f ? e : 0.2f*e);
        e = s2.y + edv.y; m1 = fmaxf(m1, e >= 0.f ? e : 0.2f*e);
        e = s2.z + edv.z; m2 = fmaxf(m2, e >= 0.f ? e : 0.2f*e);
        e = s2.w + edv.w; m3 = fmaxf(m3, e >= 0.f ? e : 0.2f*e);
    }
#pragma unroll
    for (int off = 32; off > 0; off >>= 1) {
        m0 = fmaxf(m0, __shfl_xor(m0, off, 64));
        m1 = fmaxf(m1, __shfl_xor(m1, off, 64));
        m2 = fmaxf(m2, __shfl_xor(m2, off, 64));
        m3 = fmaxf(m3, __shfl_xor(m3, off, 64));
    }
    if (lane == 0) *(float4*)&em[i*4] = make_float4(m0, m1, m2, m3);
}

// ---------------- GAT aggregate: single-pass softmax, ushort4 gather (round-10 proven) ----------------
// z stays in REGISTERS (round-11 lesson: z-in-LDS atomics serialized the block).
#define GCH 256
__global__ __launch_bounds__(256) void k_gat_agg(const bf16u* __restrict__ hg,
                                                 const float* __restrict__ es,
                                                 const float* __restrict__ ed,
                                                 const float* __restrict__ em,
                                                 const int* __restrict__ rows,
                                                 const int* __restrict__ csr,
                                                 const float* __restrict__ gbias,
                                                 bf16u* __restrict__ out) {
    __shared__ float4 se4[GCH];
    __shared__ int ssrc[GCH];
    int i = blockIdx.x, t = threadIdx.x;
    float4 edv = *(const float4*)&ed[i*4];
    float4 emv = *(const float4*)&em[i*4];
    float z0, z1, z2, z3, a0, a1, a2, a3;
    {
        float4 sv = *(const float4*)&es[i*4];
        float e;
        e = sv.x + edv.x; e = e >= 0.f ? e : 0.2f*e; z0 = __expf(e - emv.x);
        e = sv.y + edv.y; e = e >= 0.f ? e : 0.2f*e; z1 = __expf(e - emv.y);
        e = sv.z + edv.z; e = e >= 0.f ? e : 0.2f*e; z2 = __expf(e - emv.z);
        e = sv.w + edv.w; e = e >= 0.f ? e : 0.2f*e; z3 = __expf(e - emv.w);
        ushort4 u = *(const ushort4*)(hg + (size_t)i*1024 + t*4);
        a0 = z0 * bf2f(u.x); a1 = z1 * bf2f(u.y);
        a2 = z2 * bf2f(u.z); a3 = z3 * bf2f(u.w);
    }
    int e0 = rows[i], e1 = rows[i+1];
    for (int c0 = e0; c0 < e1; c0 += GCH) {
        int cn = min(GCH, e1 - c0);
        for (int j = t; j < cn; j += 256) {
            int s = csr[c0 + j];
            ssrc[j] = s;
            float4 sv = *(const float4*)&es[s*4];
            float4 v; float e;
            e = sv.x + edv.x; e = e >= 0.f ? e : 0.2f*e; v.x = __expf(e - emv.x);
            e = sv.y + edv.y; e = e >= 0.f ? e : 0.2f*e; v.y = __expf(e - emv.y);
            e = sv.z + edv.z; e = e >= 0.f ? e : 0.2f*e; v.z = __expf(e - emv.z);
            e = sv.w + edv.w; e = e >= 0.f ? e : 0.2f*e; v.w = __expf(e - emv.w);
            se4[j] = v;
        }
        __syncthreads();
        for (int j = 0; j < cn; ++j) {
            float4 ex = se4[j];
            ushort4 u = *(const ushort4*)(hg + (size_t)ssrc[j]*1024 + t*4);
            z0 += ex.x; a0 += ex.x * bf2f(u.x);
            z1 += ex.y; a1 += ex.y * bf2f(u.y);
            z2 += ex.z; a2 += ex.z * bf2f(u.z);
            z3 += ex.w; a3 += ex.w * bf2f(u.w);
        }
        __syncthreads();
    }
    float o = 0.25f * (a0/z0 + a1/z1 + a2/z2 + a3/z3);
    out[(size_t)i*256 + t] = f2bf(o + gbias[t]);
}

// ---------------- layer 4: fused BN3+ReLU + GCN aggregate (wave-per-node, ushort4) ----------------
__global__ __launch_bounds__(256) void k_gcn4_agg(const bf16u* __restrict__ h3b,
                                                  const float* __restrict__ dis,
                                                  const int* __restrict__ rows,
                                                  const int* __restrict__ csr,
                                                  const float* __restrict__ sum,
                                                  const float* __restrict__ sumsq,
                                                  const float* __restrict__ g,
                                                  const float* __restrict__ b,
                                                  bf16u* __restrict__ xab) {
    int wave = threadIdx.x >> 6, q = threadIdx.x & 63;
    int i = blockIdx.x * 4 + wave;
    int c = q * 4;
    const float invN = 1.0f / (float)N_;
    float4 sm = *(const float4*)&sum[c];
    float4 sq = *(const float4*)&sumsq[c];
    float4 gg = *(const float4*)&g[c];
    float4 bb = *(const float4*)&b[c];
    float mu, sc0, sc1, sc2, sc3, sh0, sh1, sh2, sh3;
    mu = sm.x*invN; sc0 = rsqrtf(sq.x*invN - mu*mu + EPSF)*gg.x; sh0 = bb.x - mu*sc0;
    mu = sm.y*invN; sc1 = rsqrtf(sq.y*invN - mu*mu + EPSF)*gg.y; sh1 = bb.y - mu*sc1;
    mu = sm.z*invN; sc2 = rsqrtf(sq.z*invN - mu*mu + EPSF)*gg.z; sh2 = bb.z - mu*sc2;
    mu = sm.w*invN; sc3 = rsqrtf(sq.w*invN - mu*mu + EPSF)*gg.w; sh3 = bb.w - mu*sc3;
    float di = dis[i];
    float a0, a1, a2, a3;
    {
        ushort4 u = *(const ushort4*)(h3b + (size_t)i*256 + c);
        float v, dd = di * di;
        v = fmaf(bf2f(u.x), sc0, sh0); v = v > 0.f ? v : 0.f; a0 = v * dd;
        v = fmaf(bf2f(u.y), sc1, sh1); v = v > 0.f ? v : 0.f; a1 = v * dd;
        v = fmaf(bf2f(u.z), sc2, sh2); v = v > 0.f ? v : 0.f; a2 = v * dd;
        v = fmaf(bf2f(u.w), sc3, sh3); v = v > 0.f ? v : 0.f; a3 = v * dd;
    }
    int e0 = rows[i], e1 = rows[i+1];
    for (int e = e0; e < e1; ++e) {
        int s = csr[e];
        float w = dis[s] * di;
        ushort4 u = *(const ushort4*)(h3b + (size_t)s*256 + c);
        float v;
        v = fmaf(bf2f(u.x), sc0, sh0); v = v > 0.f ? v : 0.f; a0 += v * w;
        v = fmaf(bf2f(u.y), sc1, sh1); v = v > 0.f ? v : 0.f; a1 += v * w;
        v = fmaf(bf2f(u.z), sc2, sh2); v = v > 0.f ? v : 0.f; a2 += v * w;
        v = fmaf(bf2f(u.w), sc3, sh3); v = v > 0.f ? v : 0.f; a3 += v * w;
    }
    ushort4 o;
    o.x = f2bf(a0); o.y = f2bf(a1); o.z = f2bf(a2); o.w = f2bf(a3);
    *(ushort4*)(xab + (size_t)i*256 + c) = o;
}

// ---------------- pooling with fused BN4+ReLU (+ folded fc-init blocks) ----------------
__global__ void k_pool(const bf16u* __restrict__ h4b, const int* __restrict__ gb,
                       const float* __restrict__ sum, const float* __restrict__ sumsq,
                       const float* __restrict__ g, const float* __restrict__ b,
                       const float* __restrict__ fcb,
                       float* __restrict__ pooled, float* __restrict__ out) {
    int bidx = blockIdx.x;
    int t = threadIdx.x;
    if (bidx >= 512) {                 // fc-init: out = bias (independent work)
        int i = (bidx - 512) * 256 + t;
        out[i] = fcb[i & 1023];
        return;
    }
    int gi = bidx >> 4;
    int chunk = bidx & 15;
    const float invN = 1.0f / (float)N_;
    float mu0 = sum[t] * invN;
    float sc0 = rsqrtf(sumsq[t] * invN - mu0*mu0 + EPSF) * g[t];
    float sh0 = b[t] - mu0 * sc0;
    float mu1 = sum[t+256] * invN;
    float sc1 = rsqrtf(sumsq[t+256] * invN - mu1*mu1 + EPSF) * g[t+256];
    float sh1 = b[t+256] - mu1 * sc1;
    int r0g = gb[gi], r1g = gb[gi+1];
    int n = r1g - r0g;
    if (n <= 0) return;
    int per = (n + 15) >> 4;
    int r0 = r0g + chunk * per;
    int r1 = min(r0 + per, r1g);
    if (r0 >= r1) return;
    float s0=0.f, s1=0.f, m0=0.f, m1=0.f;   // post-ReLU >= 0: max init 0 valid
    for (int r = r0; r < r1; ++r) {
        float v = fmaf(bf2f(h4b[(size_t)r*512 + t]), sc0, sh0);
        v = v > 0.f ? v : 0.f;
        s0 += v; m0 = fmaxf(m0, v);
        float w = fmaf(bf2f(h4b[(size_t)r*512 + 256 + t]), sc1, sh1);
        w = w > 0.f ? w : 0.f;
        s1 += w; m1 = fmaxf(m1, w);
    }
    atomicAdd(&pooled[gi*1024 + t], s0);
    atomicAdd(&pooled[gi*1024 + 256 + t], s1);
    atomicMax((int*)&pooled[gi*1024 + 512 + t],  __float_as_int(m0));
    atomicMax((int*)&pooled[gi*1024 + 768 + t],  __float_as_int(m1));
}

// ---------------- FC (K-split, float4, atomic reduce; mean-scale folded in) ----------------
#define FCKZ 16
#define FCKC (1024 / FCKZ)   // 64

__global__ __launch_bounds__(256) void k_fc2(const float* __restrict__ pooled,
                                             const float* __restrict__ w,
                                             const int* __restrict__ gb,
                                             float* __restrict__ out) {
    __shared__ float pr[FCKC];
    int g = blockIdx.x;
    int z = blockIdx.y;
    int t = threadIdx.x;
    int k0 = z * FCKC;
    if (t < FCKC) {
        float scale = (z < 8) ? 1.0f / fmaxf((float)(gb[g+1] - gb[g]), 1.0f) : 1.0f;
        pr[t] = pooled[g * 1024 + k0 + t] * scale;   // mean part needs 1/cnt
    }
    __syncthreads();
    int m0 = t * 4;
    float ax = 0.f, ay = 0.f, az = 0.f, aw = 0.f;
#pragma unroll 8
    for (int k = 0; k < FCKC; ++k) {
        const float4 wv = *(const float4*)&w[(size_t)(k0 + k) * 1024 + m0];
        float p = pr[k];
        ax += p * wv.x; ay += p * wv.y; az += p * wv.z; aw += p * wv.w;
    }
    atomicAdd(&out[g * 1024 + m0 + 0], ax);
    atomicAdd(&out[g * 1024 + m0 + 1], ay);
    atomicAdd(&out[g * 1024 + m0 + 2], az);
    atomicAdd(&out[g * 1024 + m0 + 3], aw);
}

// ---------------- host ----------------
extern "C" void kernel_launch(void* const* d_in, const int* in_sizes, int n_in,
                              void* d_out, int out_size, void* d_ws, size_t ws_size,
                              hipStream_t stream) {
    (void)in_sizes; (void)n_in; (void)out_size; (void)ws_size;
    const float* x       = (const float*)d_in[0];
    const int*   ei      = (const int*)d_in[1];
    const int*   batch   = (const int*)d_in[2];
    const float* gcn1_w  = (const float*)d_in[3];
    const float* gcn1_b  = (const float*)d_in[4];
    const float* sage_wl = (const float*)d_in[5];
    const float* sage_wr = (const float*)d_in[6];
    const float* sage_b  = (const float*)d_in[7];
    const float* gat_w   = (const float*)d_in[8];
    const float* gat_as  = (const float*)d_in[9];
    const float* gat_ad  = (const float*)d_in[10];
    const float* gat_b   = (const float*)d_in[11];
    const float* gcn4_w  = (const float*)d_in[12];
    const float* gcn4_b  = (const float*)d_in[13];
    const float* bn1_g   = (const float*)d_in[14];
    const float* bn1_b   = (const float*)d_in[15];
    const float* bn2_g   = (const float*)d_in[16];
    const float* bn2_b   = (const float*)d_in[17];
    const float* bn3_g   = (const float*)d_in[18];
    const float* bn3_b   = (const float*)d_in[19];
    const float* bn4_g   = (const float*)d_in[20];
    const float* bn4_b   = (const float*)d_in[21];
    const float* fc_w    = (const float*)d_in[22];
    const float* fc_b    = (const float*)d_in[23];
    float* out = (float*)d_out;

    char* w8 = (char*)d_ws;
    int*   indeg  = (int*)(w8 + OFF_INDEG);
    int*   rows   = (int*)(w8 + OFF_ROWS);
    int*   cursor = (int*)(w8 + OFF_CURSOR);
    int*   csr    = (int*)(w8 + OFF_CSR);
    float* dis    = (float*)(w8 + OFF_DIS);
    float* es     = (float*)(w8 + OFF_ES);
    float* ed     = (float*)(w8 + OFF_ED);
    float* bns    = (float*)(w8 + OFF_BNS);   // [4][512] per-layer slices
    float* bnq    = (float*)(w8 + OFF_BNQ);
    int*   gb     = (int*)(w8 + OFF_GB);
    float* pooled = (float*)(w8 + OFF_POOL);
    float* h1     = (float*)(w8 + OFF_H1);
    bf16u* ab     = (bf16u*)(w8 + OFF_AB);
    bf16u* h2p    = (bf16u*)(w8 + OFF_H2P);
    bf16u* h2b    = (bf16u*)(w8 + OFF_H2B);
    bf16u* h3b    = (bf16u*)(w8 + OFF_H3B);
    bf16u* hgat   = (bf16u*)(w8 + OFF_HGAT);
    bf16u* xa4b   = (bf16u*)(w8 + OFF_XA4B);
    bf16u* wT1    = (bf16u*)(w8 + OFF_WT1);
    bf16u* wT2    = (bf16u*)(w8 + OFF_WT2);
    bf16u* wT3    = (bf16u*)(w8 + OFF_WT3);
    bf16u* h4b    = (bf16u*)(w8 + OFF_H4B);
    float* em     = (float*)(w8 + OFF_EM);
    float* ves    = (float*)(w8 + OFF_VES);
    float* ved    = (float*)(w8 + OFF_VED);

    const int* srcE = ei;        // edge_index[0,:]
    const int* dstE = ei + E_;   // edge_index[1,:]

    const int BNB = 512;
    const int BNR = N_ / BNB;

    // ---- setup: ONE memset, then fused setup kernel (weights+gbounds+ves/ved+indeg) ----
    hipMemsetAsync(w8, 0, OFF_XA1, stream);
    k_wconv_all<<<1605, 256, 0, stream>>>(gat_w, gcn4_w, sage_wl, sage_wr, batch,
                                          gat_as, gat_ad, dstE,
                                          wT1, wT2, wT3, gb, ves, ved, indeg);
    k_scan<<<1, 1024, 0, stream>>>(indeg, rows, cursor, dis);
    k_fill<<<E_/256, 256, 0, stream>>>(srcE, dstE, cursor, csr);

    // ---- layer 1: fused GCN 5->64 (agg+matmul), BN, ReLU (bf16 mirror only) ----
    k_gcn1<<<N_/4, 256, 0, stream>>>(x, dis, rows, csr, gcn1_w, gcn1_b, h1);
    k_bn_stats<<<BNB, 256, 0, stream>>>(h1, bns, bnq, 64, BNR);
    k_bn_apply1<<<(N_*64)/256, 256, 0, stream>>>(h1, bns, bnq, bn1_g, bn1_b, ab);

    // ---- layer 2: SAGE 64->128 via single MFMA GEMM on [agg|h1], BN+attn fused ----
    k_sage_agg<<<N_/4, 256, 0, stream>>>(rows, csr, ab);
    {
        dim3 grid(1, N_/128);
        k_gemm_mfma<<<grid, 256, 0, stream>>>(ab, wT3, sage_b, (float*)h2p, 128, 128, 1);
    }
    k_bn_stats_b<<<BNB, 256, 0, stream>>>(h2p, bns + 512, bnq + 512, 128, BNR);
    k_bn_apply2b_attn<<<N_/4, 256, 0, stream>>>(h2p, bns + 512, bnq + 512, bn2_g, bn2_b,
                                                ves, ved, h2b, es, ed);

    // ---- layer 3: GAT GEMM (weight-permuted -> channel-major out), max, aggregate ----
    {
        dim3 grid(1024/128, N_/128);
        k_gemm_mfma<<<grid, 256, 0, stream>>>(h2b, wT1, nullptr, (float*)hgat, 128, 1024, 1);
    }
    k_gat_max<<<N_/4, 256, 0, stream>>>(es, ed, rows, csr, em);
    k_gat_agg<<<N_, 256, 0, stream>>>(hgat, es, ed, em, rows, csr, gat_b, h3b);
    k_bn_stats_b<<<BNB, 256, 0, stream>>>(h3b, bns + 1024, bnq + 1024, 256, BNR);

    // ---- layer 4: fused BN3+ReLU+aggregate, MFMA GEMM 256->512 (bf16 out) ----
    k_gcn4_agg<<<N_/4, 256, 0, stream>>>(h3b, dis, rows, csr, bns + 1024, bnq + 1024,
                                         bn3_g, bn3_b, xa4b);
    {
        dim3 grid(512/128, N_/128);
        k_gemm_mfma<<<grid, 256, 0, stream>>>(xa4b, wT2, gcn4_b, (float*)h4b, 256, 512, 1);
    }
    k_bn_stats_b<<<BNB, 256, 0, stream>>>(h4b, bns + 1536, bnq + 1536, 512, BNR);

    // ---- pooling with fused BN4+ReLU (+fc-init blocks) -> [32,1024] ----
    k_pool<<<640, 256, 0, stream>>>(h4b, gb, bns + 1536, bnq + 1536, bn4_g, bn4_b,
                                    fc_b, pooled, out);

    // ---- FC 1024->1024 ----
    {
        dim3 grid(G_, FCKZ);
        k_fc2<<<grid, 256, 0, stream>>>(pooled, fc_w, gb, out);
    }
}